// Round 11
// baseline (512.082 us; speedup 1.0000x reference)
//
#include <hip/hip_runtime.h>
#include <hip/hip_bf16.h>

#define NQ    40000
#define DD    256
#define NHH   8
#define NPP   8
#define DFF   1024
#define BEV   200
#define MPAD  40064   // 313 * 128

typedef __attribute__((ext_vector_type(4))) float f32x4;
typedef __attribute__((ext_vector_type(8))) short s16x8;
typedef __hip_bfloat16 bf16;

__device__ inline unsigned short f2bf(float f) {
  union { bf16 h; unsigned short u; } cv;
  cv.h = __float2bfloat16(f);
  return cv.u;
}
__device__ inline float bf2f(bf16 h) { return __bfloat162float(h); }
__device__ inline float bfs(short u) {
  union { float f; unsigned u; } c;
  c.u = ((unsigned)(unsigned short)u) << 16;
  return c.f;
}

// ---------------------------------------------------------------- weights
// dst[c*R + r] = src[r*C + c]   (src is [R][C] f32, dst is [C][R] bf16)
__global__ void transpose_cvt(const float* __restrict__ src, bf16* __restrict__ dst,
                              int R, int C) {
  int i = blockIdx.x * 256 + threadIdx.x;
  if (i >= R * C) return;
  int c = i / R, r = i % R;
  dst[i] = __float2bfloat16(src[(size_t)r * C + c]);
}

// Wq_t [256][256] bf16: row n<128: W_off col n; 128..191: W_attn; 192,193: W_ref; rest 0
__global__ void build_wq(const float* __restrict__ Woff, const float* __restrict__ Wattn,
                         const float* __restrict__ Wref, bf16* __restrict__ dst) {
  int i = blockIdx.x * 256 + threadIdx.x;   // 65536
  int n = i >> 8, k = i & 255;
  float v;
  if (n < 128)      v = Woff[k * 128 + n];
  else if (n < 192) v = Wattn[k * 64 + (n - 128)];
  else if (n < 194) v = Wref[k * 2 + (n - 192)];
  else              v = 0.f;
  dst[i] = __float2bfloat16(v);
}

// ---------------------------------------------------------------- elementwise cvt
__global__ void cvt_bf16_kernel(const float* __restrict__ src, bf16* __restrict__ dst, int n4) {
  int i = blockIdx.x * 256 + threadIdx.x;
  if (i >= n4) return;
  float4 v = ((const float4*)src)[i];
  ushort4 o;
  o.x = f2bf(v.x); o.y = f2bf(v.y); o.z = f2bf(v.z); o.w = f2bf(v.w);
  ((ushort4*)dst)[i] = o;
}

__global__ void addcvt_kernel(const float* __restrict__ a, const float* __restrict__ b,
                              bf16* __restrict__ dst, int n4) {
  int i = blockIdx.x * 256 + threadIdx.x;
  if (i >= n4) return;
  float4 va = ((const float4*)a)[i];
  float4 vb = ((const float4*)b)[i];
  ushort4 o;
  o.x = f2bf(va.x + vb.x); o.y = f2bf(va.y + vb.y);
  o.z = f2bf(va.z + vb.z); o.w = f2bf(va.w + vb.w);
  ((ushort4*)dst)[i] = o;
}

// ---------------------------------------------------------------- GEMM (register-B, zero-barrier)
// C[M][N] = A[Mpad][K](bf16) x Bt[N][K](bf16)^T.
// RATIONALE (rounds 5-10): five LDS-staged structural variants all pinned at
// MfmaUtil ~10%, ~300 TF; correct counted-vmcnt pipelining (r9) moved nothing
// -> the LDS-staging/barrier mechanism itself is the stall. This kernel has
// NO LDS, NO barriers: B held in VGPRs (per wave: 32 ncols x 256 k = 64
// VGPR), A streamed global->VGPR. Each a-frag load covers 16 full 64B lines
// (lanes 0-15 rows, lane>>4 picks the 16B sub-chunk); the 4 column-waves
// re-read identical A lines via L1/L2. K>256 handled as segments with B-regs
// reloaded per segment (FFN2: 4 segments).
// A-loads in two explicit half-batches of 16 (static reg indices; caps
// in-flight payload -> no scratch spills, round-2 lesson).
// Tile 128x128, 512 thr = 8 waves (2M x 4N), wave 64x32 = 4x2 frags.
// XCD chunk swizzle retained (round-4/5: FETCH 81->12 MB).
template<int NSEG, bool RELU>
__global__ void gemm_rb(const bf16* __restrict__ A, const bf16* __restrict__ Bt,
                        int K, int Ntiles, int N,
                        const float* __restrict__ bias, float biasScale,
                        const bf16* __restrict__ addB, float addScale,
                        bf16* __restrict__ outB, float* __restrict__ outF, int Mvalid) {
  const int tid  = threadIdx.x;
  const int wave = tid >> 6, lane = tid & 63;
  // XCD-aware chunked remap (bijective for any nwg)
  const int nwg = gridDim.x;
  const int orig = blockIdx.x;
  const int q8 = nwg >> 3, r8 = nwg & 7;
  const int xcd = orig & 7, idx = orig >> 3;
  const int wg = (xcd < r8 ? xcd * (q8 + 1) : r8 * (q8 + 1) + (xcd - r8) * q8) + idx;
  const int tm = wg / Ntiles, tn = wg % Ntiles;
  const int wr = wave >> 2, wc = wave & 3;   // 2M x 4N wave grid
  const int r  = lane & 15, hi = lane >> 4;

  f32x4 acc[4][2];
#pragma unroll
  for (int i = 0; i < 4; ++i)
#pragma unroll
    for (int j = 0; j < 2; ++j) {
      f32x4 z = {0.f, 0.f, 0.f, 0.f};
      acc[i][j] = z;
    }

  // row base pointers (lane's own row r folded in)
  const bf16* arow = A  + (size_t)(tm * 128 + wr * 64 + r) * K + hi * 8;
  const bf16* brow = Bt + (size_t)(tn * 128 + wc * 32 + r) * K + hi * 8;

#pragma unroll
  for (int seg = 0; seg < NSEG; ++seg) {
    const int k0 = seg * 256;
    // B fragments for this K-segment: 2 n-frags x 8 k-chunks = 64 VGPR
    s16x8 bf_[2][8];
#pragma unroll
    for (int nf = 0; nf < 2; ++nf)
#pragma unroll
      for (int c = 0; c < 8; ++c)
        bf_[nf][c] = *(const s16x8*)(brow + (size_t)nf * 16 * K + k0 + c * 32);
    // A in two half-batches of 16 loads (static indices throughout)
#pragma unroll
    for (int hf = 0; hf < 2; ++hf) {
      s16x8 af[4][4];
#pragma unroll
      for (int mf = 0; mf < 4; ++mf)
#pragma unroll
        for (int cc = 0; cc < 4; ++cc)
          af[mf][cc] = *(const s16x8*)(arow + (size_t)mf * 16 * K + k0 + (hf * 4 + cc) * 32);
#pragma unroll
      for (int cc = 0; cc < 4; ++cc)
#pragma unroll
        for (int mf = 0; mf < 4; ++mf)
#pragma unroll
          for (int nf = 0; nf < 2; ++nf)
            acc[mf][nf] = __builtin_amdgcn_mfma_f32_16x16x32_bf16(
                af[mf][cc], bf_[nf][hf * 4 + cc], acc[mf][nf], 0, 0, 0);
    }
  }

  // epilogue: C/D frag mapping col = lane&15, row = (lane>>4)*4 + j
#pragma unroll
  for (int mf = 0; mf < 4; ++mf) {
#pragma unroll
    for (int nf = 0; nf < 2; ++nf) {
      const int gn = tn * 128 + wc * 32 + nf * 16 + r;
      const float bval = bias ? biasScale * bias[gn] : 0.f;
#pragma unroll
      for (int j2 = 0; j2 < 4; ++j2) {
        const int gm = tm * 128 + wr * 64 + mf * 16 + hi * 4 + j2;
        float v = acc[mf][nf][j2] + bval;
        if (addB && gm < Mvalid) v += addScale * bf2f(addB[(size_t)gm * N + gn]);
        if (RELU) v = fmaxf(v, 0.f);
        if (outB) outB[(size_t)gm * N + gn] = __float2bfloat16(v);
        if (outF && gm < Mvalid) outF[(size_t)gm * N + gn] = v;
      }
    }
  }
}

// ---------------------------------------------------------------- samp finalize
// raw[q][0..127]=off logits, [128..191]=attn logits, [192..193]=ref logits (no bias yet)
// -> samp[q][hp] = (px, py, attn_weight)
__global__ void finalize_kernel(const bf16* __restrict__ raw, const float* __restrict__ b_off,
                                const float* __restrict__ b_attn, const float* __restrict__ b_ref,
                                float* __restrict__ samp) {
  __shared__ float r[4][256];
  const int tid = threadIdx.x;
  const int q0 = blockIdx.x * 4;
#pragma unroll
  for (int i = 0; i < 4; ++i) {
    int e = tid + i * 256;
    int ql = e >> 8, k = e & 255;
    r[ql][k] = bf2f(raw[(size_t)(q0 + ql) * 256 + k]);
  }
  __syncthreads();
  const int ql = tid >> 6, hp = tid & 63;
  const int h = hp >> 3, p = hp & 7;
  float v[8];
  float m = -1e30f;
#pragma unroll
  for (int pp = 0; pp < 8; ++pp) {
    v[pp] = r[ql][128 + h * 8 + pp] + b_attn[h * 8 + pp];
    m = fmaxf(m, v[pp]);
  }
  float s = 0.f;
#pragma unroll
  for (int pp = 0; pp < 8; ++pp) { v[pp] = expf(v[pp] - m); s += v[pp]; }
  const float w = v[p] / s;
  const float sx = 1.f / (1.f + expf(-(r[ql][192] + b_ref[0])));
  const float sy = 1.f / (1.f + expf(-(r[ql][193] + b_ref[1])));
  // px = loc_x*BEV_W - 0.5 = sigmoid(ref_x)*W + off_x - 0.5   (off normalizer = W)
  const float px = sx * (float)BEV + (r[ql][hp * 2 + 0] + b_off[hp * 2 + 0]) - 0.5f;
  const float py = sy * (float)BEV + (r[ql][hp * 2 + 1] + b_off[hp * 2 + 1]) - 0.5f;
  const size_t o = ((size_t)(q0 + ql) * 64 + hp) * 3;
  samp[o] = px; samp[o + 1] = py; samp[o + 2] = w;
}

// ---------------------------------------------------------------- deform gather
// 8 queries per block; 32 threads per query: thread = (head, dword-group).
// Each thread accumulates 8 channels with 16B s16x8 loads per corner.
// Zero-padding via clamped index + zeroed weight (branch-free).
// unroll 2 (not 8): caps in-flight load payload at ~32 VGPR -> no scratch
// spills (round-2 showed 177MB hidden spill writes at full unroll).
__global__ __launch_bounds__(256, 4)
void deform_kernel(const float* __restrict__ samp, const bf16* __restrict__ val,
                   bf16* __restrict__ out) {
  __shared__ float s[8 * 192];
  const int tid = threadIdx.x;
  const int q0 = blockIdx.x * 8;
#pragma unroll
  for (int i = 0; i < 6; ++i) {
    const int e = tid + i * 256;
    s[e] = samp[(size_t)q0 * 192 + e];
  }
  __syncthreads();
  const int ql = tid >> 5;          // 0..7 query within block
  const int lane5 = tid & 31;
  const int h = lane5 >> 2;         // 0..7 head
  const int dg = lane5 & 3;         // 0..3 dword-group (8 channels)
  const float* sp = s + ql * 192 + h * 24;
  const bf16* vb = val + h * 32 + dg * 8;

  float acc[8] = {0.f, 0.f, 0.f, 0.f, 0.f, 0.f, 0.f, 0.f};
#pragma unroll 2
  for (int p = 0; p < 8; ++p) {
    const float px = sp[p * 3 + 0], py = sp[p * 3 + 1], w = sp[p * 3 + 2];
    const float xf = floorf(px), yf = floorf(py);
    const int x0 = (int)xf, y0 = (int)yf;
    const float lx = px - xf, ly = py - yf;
    const float xa = (x0 >= 0 && x0 < BEV) ? 1.f : 0.f;
    const float xb = (x0 + 1 >= 0 && x0 + 1 < BEV) ? 1.f : 0.f;
    const float ya = (y0 >= 0 && y0 < BEV) ? 1.f : 0.f;
    const float yb = (y0 + 1 >= 0 && y0 + 1 < BEV) ? 1.f : 0.f;
    const float w00 = w * (1.f - lx) * (1.f - ly) * xa * ya;
    const float w10 = w * lx * (1.f - ly) * xb * ya;
    const float w01 = w * (1.f - lx) * ly * xa * yb;
    const float w11 = w * lx * ly * xb * yb;
    const int cx0 = min(max(x0, 0), BEV - 1);
    const int cx1 = min(max(x0 + 1, 0), BEV - 1);
    const int cy0 = min(max(y0, 0), BEV - 1) * BEV;
    const int cy1 = min(max(y0 + 1, 0), BEV - 1) * BEV;
    const s16x8 v00 = *(const s16x8*)(vb + (size_t)(cy0 + cx0) * 256);
    const s16x8 v10 = *(const s16x8*)(vb + (size_t)(cy0 + cx1) * 256);
    const s16x8 v01 = *(const s16x8*)(vb + (size_t)(cy1 + cx0) * 256);
    const s16x8 v11 = *(const s16x8*)(vb + (size_t)(cy1 + cx1) * 256);
#pragma unroll
    for (int j = 0; j < 8; ++j) {
      acc[j] += w00 * bfs(v00[j]) + w10 * bfs(v10[j])
              + w01 * bfs(v01[j]) + w11 * bfs(v11[j]);
    }
  }
  s16x8 o;
#pragma unroll
  for (int j = 0; j < 8; ++j) o[j] = (short)f2bf(acc[j]);
  *(s16x8*)(out + (size_t)(q0 + ql) * 256 + h * 32 + dg * 8) = o;
}

// ---------------------------------------------------------------- host
extern "C" void kernel_launch(void* const* d_in, const int* in_sizes, int n_in,
                              void* d_out, int out_size, void* d_ws, size_t ws_size,
                              hipStream_t stream) {
  const float* B0     = (const float*)d_in[0];
  const float* B1     = (const float*)d_in[1];
  const float* qe     = (const float*)d_in[2];
  const float* W_ref  = (const float*)d_in[3];
  const float* b_ref  = (const float*)d_in[4];
  const float* W_off  = (const float*)d_in[5];
  const float* b_off  = (const float*)d_in[6];
  const float* W_attn = (const float*)d_in[7];
  const float* b_attn = (const float*)d_in[8];
  const float* W_val  = (const float*)d_in[9];
  const float* b_val  = (const float*)d_in[10];
  const float* W_out  = (const float*)d_in[11];
  const float* b_out  = (const float*)d_in[12];
  const float* W_ffn1 = (const float*)d_in[13];
  const float* b_ffn1 = (const float*)d_in[14];
  const float* W_ffn2 = (const float*)d_in[15];
  const float* b_ffn2 = (const float*)d_in[16];
  float* out = (float*)d_out;
  char* ws = (char*)d_ws;

  // workspace layout (bytes)
  const size_t SZ_MAT = (size_t)MPAD * 256 * 2;        // 20,512,768
  const size_t VAL_OFF    = 0;                          // val bf16
  const size_t RAW_OFF    = SZ_MAT;                     // raw / deform (aliased, serialized)
  const size_t BSH_OFF    = 2 * SZ_MAT;                 // Bshort bf16
  const size_t H_OFF      = 3 * SZ_MAT;                 // H [MPAD][1024] bf16 (82MB)
  const size_t QE_OFF     = H_OFF;                      // qe bf16 (aliased into H, used early)
  const size_t VSUM_OFF   = H_OFF + SZ_MAT;             // vsum bf16 (aliased into H)
  const size_t H_BYTES    = (size_t)MPAD * 1024 * 2;
  const size_t SAMP_OFF   = H_OFF + H_BYTES;            // samp f32 [NQ][64][3]
  const size_t SAMP_BYTES = (size_t)NQ * 192 * 4;
  const size_t WQ_OFF     = SAMP_OFF + SAMP_BYTES;
  const size_t WVAL_OFF   = WQ_OFF   + 256 * 256 * 2;
  const size_t WOUT_OFF   = WVAL_OFF + 256 * 256 * 2;
  const size_t WF1_OFF    = WOUT_OFF + 256 * 256 * 2;
  const size_t WF2_OFF    = WF1_OFF  + 1024 * 256 * 2;

  bf16* valb  = (bf16*)(ws + VAL_OFF);
  bf16* rawb  = (bf16*)(ws + RAW_OFF);
  bf16* defb  = rawb;                    // aliased (raw dead after finalize)
  bf16* bshb  = (bf16*)(ws + BSH_OFF);
  bf16* hbuf  = (bf16*)(ws + H_OFF);
  bf16* qeb   = (bf16*)(ws + QE_OFF);
  bf16* vsum  = (bf16*)(ws + VSUM_OFF);
  float* samp = (float*)(ws + SAMP_OFF);
  bf16* wq    = (bf16*)(ws + WQ_OFF);
  bf16* wval  = (bf16*)(ws + WVAL_OFF);
  bf16* wout  = (bf16*)(ws + WOUT_OFF);
  bf16* wf1   = (bf16*)(ws + WF1_OFF);
  bf16* wf2   = (bf16*)(ws + WF2_OFF);

  const int n4 = NQ * 256 / 4;           // 2,560,000
  const int MT = MPAD / 128;             // 313

  // weights -> transposed bf16
  build_wq<<<256, 256, 0, stream>>>(W_off, W_attn, W_ref, wq);
  transpose_cvt<<<(256 * 256 + 255) / 256, 256, 0, stream>>>(W_val, wval, 256, 256);
  transpose_cvt<<<(256 * 256 + 255) / 256, 256, 0, stream>>>(W_out, wout, 256, 256);
  transpose_cvt<<<(256 * 1024 + 255) / 256, 256, 0, stream>>>(W_ffn1, wf1, 256, 1024);
  transpose_cvt<<<(1024 * 256 + 255) / 256, 256, 0, stream>>>(W_ffn2, wf2, 1024, 256);

  // activations -> bf16
  cvt_bf16_kernel<<<n4 / 256, 256, 0, stream>>>(qe, qeb, n4);
  addcvt_kernel<<<n4 / 256, 256, 0, stream>>>(B0, B1, vsum, n4);

  // raw logits = q @ Wq^T
  gemm_rb<1, false><<<MT * 2, 512, 0, stream>>>(qeb, wq, 256, 2, 256,
                                                nullptr, 0.f, nullptr, 0.f,
                                                rawb, nullptr, NQ);
  finalize_kernel<<<NQ / 4, 256, 0, stream>>>(rawb, b_off, b_attn, b_ref, samp);

  // val = (B0+B1) @ W_val + 2*b_val
  gemm_rb<1, false><<<MT * 2, 512, 0, stream>>>(vsum, wval, 256, 2, 256,
                                                b_val, 2.f, nullptr, 0.f,
                                                valb, nullptr, NQ);

  deform_kernel<<<NQ / 8, 256, 0, stream>>>(samp, valb, defb);

  // B_short = deform @ W_out + 2*b_out + 2*q   (bf16 residual)
  gemm_rb<1, false><<<MT * 2, 512, 0, stream>>>(defb, wout, 256, 2, 256,
                                                b_out, 2.f, qeb, 2.f,
                                                bshb, nullptr, NQ);

  // H = relu(B_short @ W_ffn1 + b_ffn1)
  gemm_rb<1, true><<<MT * 8, 512, 0, stream>>>(bshb, wf1, 256, 8, 1024,
                                               b_ffn1, 1.f, nullptr, 0.f,
                                               hbuf, nullptr, NQ);

  // out = B_short + H @ W_ffn2 + b_ffn2   (K=1024 -> 4 B-reg segments)
  gemm_rb<4, false><<<MT * 2, 512, 0, stream>>>(hbuf, wf2, 1024, 2, 256,
                                                b_ffn2, 1.f, bshb, 1.f,
                                                nullptr, out, NQ);
}

// Round 12
// 331.460 us; speedup vs baseline: 1.5449x; 1.5449x over previous
//
#include <hip/hip_runtime.h>
#include <hip/hip_bf16.h>

#define NQ    40000
#define DD    256
#define NHH   8
#define NPP   8
#define DFF   1024
#define BEV   200
#define MPAD  40064   // 626 * 64

typedef __attribute__((ext_vector_type(4))) float f32x4;
typedef __attribute__((ext_vector_type(8))) short s16x8;
typedef __hip_bfloat16 bf16;

#define AS1(p) ((const __attribute__((address_space(1))) void*)(p))
#define AS3(p) ((__attribute__((address_space(3))) void*)(p))

__device__ inline unsigned short f2bf(float f) {
  union { bf16 h; unsigned short u; } cv;
  cv.h = __float2bfloat16(f);
  return cv.u;
}
__device__ inline float bf2f(bf16 h) { return __bfloat162float(h); }
__device__ inline float bfs(short u) {
  union { float f; unsigned u; } c;
  c.u = ((unsigned)(unsigned short)u) << 16;
  return c.f;
}

// ---------------------------------------------------------------- weights
__global__ void transpose_cvt(const float* __restrict__ src, bf16* __restrict__ dst,
                              int R, int C) {
  int i = blockIdx.x * 256 + threadIdx.x;
  if (i >= R * C) return;
  int c = i / R, r = i % R;
  dst[i] = __float2bfloat16(src[(size_t)r * C + c]);
}

__global__ void build_wq(const float* __restrict__ Woff, const float* __restrict__ Wattn,
                         const float* __restrict__ Wref, bf16* __restrict__ dst) {
  int i = blockIdx.x * 256 + threadIdx.x;   // 65536
  int n = i >> 8, k = i & 255;
  float v;
  if (n < 128)      v = Woff[k * 128 + n];
  else if (n < 192) v = Wattn[k * 64 + (n - 128)];
  else if (n < 194) v = Wref[k * 2 + (n - 192)];
  else              v = 0.f;
  dst[i] = __float2bfloat16(v);
}

// ---------------------------------------------------------------- elementwise cvt
__global__ void cvt_bf16_kernel(const float* __restrict__ src, bf16* __restrict__ dst, int n4) {
  int i = blockIdx.x * 256 + threadIdx.x;
  if (i >= n4) return;
  float4 v = ((const float4*)src)[i];
  ushort4 o;
  o.x = f2bf(v.x); o.y = f2bf(v.y); o.z = f2bf(v.z); o.w = f2bf(v.w);
  ((ushort4*)dst)[i] = o;
}

__global__ void addcvt_kernel(const float* __restrict__ a, const float* __restrict__ b,
                              bf16* __restrict__ dst, int n4) {
  int i = blockIdx.x * 256 + threadIdx.x;
  if (i >= n4) return;
  float4 va = ((const float4*)a)[i];
  float4 vb = ((const float4*)b)[i];
  ushort4 o;
  o.x = f2bf(va.x + vb.x); o.y = f2bf(va.y + vb.y);
  o.z = f2bf(va.z + vb.z); o.w = f2bf(va.w + vb.w);
  ((ushort4*)dst)[i] = o;
}

// ---------------------------------------------------------------- GEMM (single-wave, barrier-free)
// C[M][N] = A[Mpad][K](bf16) x Bt[N][K](bf16)^T.
// RATIONALE (r5-r11): every barrier-synced LDS variant pinned at MfmaUtil
// ~10% (lockstep stalls); register-resident-B (r11) defeated by regalloc.
// This kernel: ONE wave per block (64 thr), tile 64x64, BK=32, LDS dbuf
// 2x8KB, COUNTED vmcnt with ZERO barriers -- single-wave blocks make the
// buffer hand-off race-free by in-order issue (stage into a buffer only
// after its ds_reads were consumed by MFMAs). Per iter: stage next tile
// (8 global_load_lds) -> vmcnt(8) (current arrived, next stays in flight)
// -> sched_barrier(0) (rule #18) -> 8 ds_read_b128 + 16 MFMA.
// ~10 independent waves/CU, fully desynchronized -> TLP latency hiding
// without collective stalls. XCD chunk swizzle retained.
template<bool RELU>
__global__ __launch_bounds__(64)
void gemm_sw(const bf16* __restrict__ A, const bf16* __restrict__ Bt,
             int K, int Ntiles, int N,
             const float* __restrict__ bias, float biasScale,
             const bf16* __restrict__ addB, float addScale,
             bf16* __restrict__ outB, float* __restrict__ outF, int Mvalid) {
  __shared__ __align__(16) char smem[2][8192];   // per buf: A [64][32] 4KB | B [64][32] 4KB
  const int lane = threadIdx.x;
  const int r = lane & 15, hi = lane >> 4;
  // XCD-aware chunked remap (bijective for any nwg)
  const int nwg = gridDim.x;
  const int orig = blockIdx.x;
  const int q8 = nwg >> 3, r8 = nwg & 7;
  const int xcd = orig & 7, idx = orig >> 3;
  const int wg = (xcd < r8 ? xcd * (q8 + 1) : r8 * (q8 + 1) + (xcd - r8) * q8) + idx;
  const int tm = wg / Ntiles, tn = wg % Ntiles;

  f32x4 acc[4][4];
#pragma unroll
  for (int i = 0; i < 4; ++i)
#pragma unroll
    for (int j = 0; j < 4; ++j) {
      f32x4 z = {0.f, 0.f, 0.f, 0.f};
      acc[i][j] = z;
    }

  const char* Ab = (const char*)A;
  const char* Bb = (const char*)Bt;
  const int nK = K >> 5;

  auto stage = [&](int buf, int kt) {
#pragma unroll
    for (int i = 0; i < 8; ++i) {
      const int p0 = i << 10;                // 1KB per instruction
      const char* g;
      if (p0 < 4096) {                       // A: [64][32] bf16, row = 64B
        const int pl = p0 + lane * 16;
        const int row = pl >> 6, cb = pl & 63;
        g = Ab + ((size_t)(tm * 64 + row) * K + kt * 32) * 2 + cb;
      } else {                               // B: [64][32] bf16 (rows = C-cols)
        const int pl = p0 - 4096 + lane * 16;
        const int row = pl >> 6, cb = pl & 63;
        g = Bb + ((size_t)(tn * 64 + row) * K + kt * 32) * 2 + cb;
      }
      __builtin_amdgcn_global_load_lds(AS1(g), AS3(&smem[buf][p0]), 16, 0, 0);
    }
  };

  stage(0, 0);
  for (int kt = 0; kt < nK; ++kt) {
    const int cur = kt & 1;
    if (kt + 1 < nK) {
      stage(cur ^ 1, kt + 1);                // prefetch next tile
      asm volatile("s_waitcnt vmcnt(8)" ::: "memory");  // current tile arrived
    } else {
      asm volatile("s_waitcnt vmcnt(0)" ::: "memory");
    }
    __builtin_amdgcn_sched_barrier(0);       // rule #18: pin ds_reads after wait
    const char* sbuf = smem[cur];
    s16x8 af[4], bfr[4];
#pragma unroll
    for (int mr = 0; mr < 4; ++mr)
      af[mr] = *(const s16x8*)(sbuf + (mr * 16 + r) * 64 + hi * 16);
#pragma unroll
    for (int nr = 0; nr < 4; ++nr)
      bfr[nr] = *(const s16x8*)(sbuf + 4096 + (nr * 16 + r) * 64 + hi * 16);
#pragma unroll
    for (int mr = 0; mr < 4; ++mr)
#pragma unroll
      for (int nr = 0; nr < 4; ++nr)
        acc[mr][nr] = __builtin_amdgcn_mfma_f32_16x16x32_bf16(af[mr], bfr[nr], acc[mr][nr], 0, 0, 0);
  }

  // epilogue: C/D frag mapping col = lane&15, row = (lane>>4)*4 + j
#pragma unroll
  for (int mr = 0; mr < 4; ++mr) {
#pragma unroll
    for (int nr = 0; nr < 4; ++nr) {
      const int gn = tn * 64 + nr * 16 + r;
      const float bval = bias ? biasScale * bias[gn] : 0.f;
#pragma unroll
      for (int j2 = 0; j2 < 4; ++j2) {
        const int gm = tm * 64 + mr * 16 + hi * 4 + j2;
        float v = acc[mr][nr][j2] + bval;
        if (addB && gm < Mvalid) v += addScale * bf2f(addB[(size_t)gm * N + gn]);
        if (RELU) v = fmaxf(v, 0.f);
        if (outB) outB[(size_t)gm * N + gn] = __float2bfloat16(v);
        if (outF && gm < Mvalid) outF[(size_t)gm * N + gn] = v;
      }
    }
  }
}

// ---------------------------------------------------------------- samp finalize
__global__ void finalize_kernel(const bf16* __restrict__ raw, const float* __restrict__ b_off,
                                const float* __restrict__ b_attn, const float* __restrict__ b_ref,
                                float* __restrict__ samp) {
  __shared__ float r[4][256];
  const int tid = threadIdx.x;
  const int q0 = blockIdx.x * 4;
#pragma unroll
  for (int i = 0; i < 4; ++i) {
    int e = tid + i * 256;
    int ql = e >> 8, k = e & 255;
    r[ql][k] = bf2f(raw[(size_t)(q0 + ql) * 256 + k]);
  }
  __syncthreads();
  const int ql = tid >> 6, hp = tid & 63;
  const int h = hp >> 3, p = hp & 7;
  float v[8];
  float m = -1e30f;
#pragma unroll
  for (int pp = 0; pp < 8; ++pp) {
    v[pp] = r[ql][128 + h * 8 + pp] + b_attn[h * 8 + pp];
    m = fmaxf(m, v[pp]);
  }
  float s = 0.f;
#pragma unroll
  for (int pp = 0; pp < 8; ++pp) { v[pp] = expf(v[pp] - m); s += v[pp]; }
  const float w = v[p] / s;
  const float sx = 1.f / (1.f + expf(-(r[ql][192] + b_ref[0])));
  const float sy = 1.f / (1.f + expf(-(r[ql][193] + b_ref[1])));
  const float px = sx * (float)BEV + (r[ql][hp * 2 + 0] + b_off[hp * 2 + 0]) - 0.5f;
  const float py = sy * (float)BEV + (r[ql][hp * 2 + 1] + b_off[hp * 2 + 1]) - 0.5f;
  const size_t o = ((size_t)(q0 + ql) * 64 + hp) * 3;
  samp[o] = px; samp[o + 1] = py; samp[o + 2] = w;
}

// ---------------------------------------------------------------- deform gather
__global__ __launch_bounds__(256, 4)
void deform_kernel(const float* __restrict__ samp, const bf16* __restrict__ val,
                   bf16* __restrict__ out) {
  __shared__ float s[8 * 192];
  const int tid = threadIdx.x;
  const int q0 = blockIdx.x * 8;
#pragma unroll
  for (int i = 0; i < 6; ++i) {
    const int e = tid + i * 256;
    s[e] = samp[(size_t)q0 * 192 + e];
  }
  __syncthreads();
  const int ql = tid >> 5;          // 0..7 query within block
  const int lane5 = tid & 31;
  const int h = lane5 >> 2;         // 0..7 head
  const int dg = lane5 & 3;         // 0..3 dword-group (8 channels)
  const float* sp = s + ql * 192 + h * 24;
  const bf16* vb = val + h * 32 + dg * 8;

  float acc[8] = {0.f, 0.f, 0.f, 0.f, 0.f, 0.f, 0.f, 0.f};
#pragma unroll 2
  for (int p = 0; p < 8; ++p) {
    const float px = sp[p * 3 + 0], py = sp[p * 3 + 1], w = sp[p * 3 + 2];
    const float xf = floorf(px), yf = floorf(py);
    const int x0 = (int)xf, y0 = (int)yf;
    const float lx = px - xf, ly = py - yf;
    const float xa = (x0 >= 0 && x0 < BEV) ? 1.f : 0.f;
    const float xb = (x0 + 1 >= 0 && x0 + 1 < BEV) ? 1.f : 0.f;
    const float ya = (y0 >= 0 && y0 < BEV) ? 1.f : 0.f;
    const float yb = (y0 + 1 >= 0 && y0 + 1 < BEV) ? 1.f : 0.f;
    const float w00 = w * (1.f - lx) * (1.f - ly) * xa * ya;
    const float w10 = w * lx * (1.f - ly) * xb * ya;
    const float w01 = w * (1.f - lx) * ly * xa * yb;
    const float w11 = w * lx * ly * xb * yb;
    const int cx0 = min(max(x0, 0), BEV - 1);
    const int cx1 = min(max(x0 + 1, 0), BEV - 1);
    const int cy0 = min(max(y0, 0), BEV - 1) * BEV;
    const int cy1 = min(max(y0 + 1, 0), BEV - 1) * BEV;
    const s16x8 v00 = *(const s16x8*)(vb + (size_t)(cy0 + cx0) * 256);
    const s16x8 v10 = *(const s16x8*)(vb + (size_t)(cy0 + cx1) * 256);
    const s16x8 v01 = *(const s16x8*)(vb + (size_t)(cy1 + cx0) * 256);
    const s16x8 v11 = *(const s16x8*)(vb + (size_t)(cy1 + cx1) * 256);
#pragma unroll
    for (int j = 0; j < 8; ++j) {
      acc[j] += w00 * bfs(v00[j]) + w10 * bfs(v10[j])
              + w01 * bfs(v01[j]) + w11 * bfs(v11[j]);
    }
  }
  s16x8 o;
#pragma unroll
  for (int j = 0; j < 8; ++j) o[j] = (short)f2bf(acc[j]);
  *(s16x8*)(out + (size_t)(q0 + ql) * 256 + h * 32 + dg * 8) = o;
}

// ---------------------------------------------------------------- host
extern "C" void kernel_launch(void* const* d_in, const int* in_sizes, int n_in,
                              void* d_out, int out_size, void* d_ws, size_t ws_size,
                              hipStream_t stream) {
  const float* B0     = (const float*)d_in[0];
  const float* B1     = (const float*)d_in[1];
  const float* qe     = (const float*)d_in[2];
  const float* W_ref  = (const float*)d_in[3];
  const float* b_ref  = (const float*)d_in[4];
  const float* W_off  = (const float*)d_in[5];
  const float* b_off  = (const float*)d_in[6];
  const float* W_attn = (const float*)d_in[7];
  const float* b_attn = (const float*)d_in[8];
  const float* W_val  = (const float*)d_in[9];
  const float* b_val  = (const float*)d_in[10];
  const float* W_out  = (const float*)d_in[11];
  const float* b_out  = (const float*)d_in[12];
  const float* W_ffn1 = (const float*)d_in[13];
  const float* b_ffn1 = (const float*)d_in[14];
  const float* W_ffn2 = (const float*)d_in[15];
  const float* b_ffn2 = (const float*)d_in[16];
  float* out = (float*)d_out;
  char* ws = (char*)d_ws;

  // workspace layout (bytes)
  const size_t SZ_MAT = (size_t)MPAD * 256 * 2;        // 20,512,768
  const size_t VAL_OFF    = 0;                          // val bf16
  const size_t RAW_OFF    = SZ_MAT;                     // raw / deform (aliased, serialized)
  const size_t BSH_OFF    = 2 * SZ_MAT;                 // Bshort bf16
  const size_t H_OFF      = 3 * SZ_MAT;                 // H [MPAD][1024] bf16 (82MB)
  const size_t QE_OFF     = H_OFF;                      // qe bf16 (aliased into H, used early)
  const size_t VSUM_OFF   = H_OFF + SZ_MAT;             // vsum bf16 (aliased into H)
  const size_t H_BYTES    = (size_t)MPAD * 1024 * 2;
  const size_t SAMP_OFF   = H_OFF + H_BYTES;            // samp f32 [NQ][64][3]
  const size_t SAMP_BYTES = (size_t)NQ * 192 * 4;
  const size_t WQ_OFF     = SAMP_OFF + SAMP_BYTES;
  const size_t WVAL_OFF   = WQ_OFF   + 256 * 256 * 2;
  const size_t WOUT_OFF   = WVAL_OFF + 256 * 256 * 2;
  const size_t WF1_OFF    = WOUT_OFF + 256 * 256 * 2;
  const size_t WF2_OFF    = WF1_OFF  + 1024 * 256 * 2;

  bf16* valb  = (bf16*)(ws + VAL_OFF);
  bf16* rawb  = (bf16*)(ws + RAW_OFF);
  bf16* defb  = rawb;                    // aliased (raw dead after finalize)
  bf16* bshb  = (bf16*)(ws + BSH_OFF);
  bf16* hbuf  = (bf16*)(ws + H_OFF);
  bf16* qeb   = (bf16*)(ws + QE_OFF);
  bf16* vsum  = (bf16*)(ws + VSUM_OFF);
  float* samp = (float*)(ws + SAMP_OFF);
  bf16* wq    = (bf16*)(ws + WQ_OFF);
  bf16* wval  = (bf16*)(ws + WVAL_OFF);
  bf16* wout  = (bf16*)(ws + WOUT_OFF);
  bf16* wf1   = (bf16*)(ws + WF1_OFF);
  bf16* wf2   = (bf16*)(ws + WF2_OFF);

  const int n4 = NQ * 256 / 4;           // 2,560,000
  const int MT = MPAD / 64;              // 626

  // weights -> transposed bf16
  build_wq<<<256, 256, 0, stream>>>(W_off, W_attn, W_ref, wq);
  transpose_cvt<<<(256 * 256 + 255) / 256, 256, 0, stream>>>(W_val, wval, 256, 256);
  transpose_cvt<<<(256 * 256 + 255) / 256, 256, 0, stream>>>(W_out, wout, 256, 256);
  transpose_cvt<<<(256 * 1024 + 255) / 256, 256, 0, stream>>>(W_ffn1, wf1, 256, 1024);
  transpose_cvt<<<(1024 * 256 + 255) / 256, 256, 0, stream>>>(W_ffn2, wf2, 1024, 256);

  // activations -> bf16
  cvt_bf16_kernel<<<n4 / 256, 256, 0, stream>>>(qe, qeb, n4);
  addcvt_kernel<<<n4 / 256, 256, 0, stream>>>(B0, B1, vsum, n4);

  // raw logits = q @ Wq^T
  gemm_sw<false><<<MT * 4, 64, 0, stream>>>(qeb, wq, 256, 4, 256,
                                            nullptr, 0.f, nullptr, 0.f,
                                            rawb, nullptr, NQ);
  finalize_kernel<<<NQ / 4, 256, 0, stream>>>(rawb, b_off, b_attn, b_ref, samp);

  // val = (B0+B1) @ W_val + 2*b_val
  gemm_sw<false><<<MT * 4, 64, 0, stream>>>(vsum, wval, 256, 4, 256,
                                            b_val, 2.f, nullptr, 0.f,
                                            valb, nullptr, NQ);

  deform_kernel<<<NQ / 8, 256, 0, stream>>>(samp, valb, defb);

  // B_short = deform @ W_out + 2*b_out + 2*q   (bf16 residual)
  gemm_sw<false><<<MT * 4, 64, 0, stream>>>(defb, wout, 256, 4, 256,
                                            b_out, 2.f, qeb, 2.f,
                                            bshb, nullptr, NQ);

  // H = relu(B_short @ W_ffn1 + b_ffn1)
  gemm_sw<true><<<MT * 16, 64, 0, stream>>>(bshb, wf1, 256, 16, 1024,
                                            b_ffn1, 1.f, nullptr, 0.f,
                                            hbuf, nullptr, NQ);

  // out = B_short + H @ W_ffn2 + b_ffn2   (sole f32 writer of d_out)
  gemm_sw<false><<<MT * 4, 64, 0, stream>>>(hbuf, wf2, 1024, 4, 256,
                                            b_ffn2, 1.f, bshb, 1.f,
                                            nullptr, out, NQ);
}

// Round 13
// 316.418 us; speedup vs baseline: 1.6184x; 1.0475x over previous
//
#include <hip/hip_runtime.h>
#include <hip/hip_bf16.h>

#define NQ    40000
#define DD    256
#define NHH   8
#define NPP   8
#define DFF   1024
#define BEV   200
#define MPAD  40192   // 157 * 256

typedef __attribute__((ext_vector_type(4))) float f32x4;
typedef __attribute__((ext_vector_type(8))) short s16x8;
typedef __hip_bfloat16 bf16;

#define AS1(p) ((const __attribute__((address_space(1))) void*)(p))
#define AS3(p) ((__attribute__((address_space(3))) void*)(p))

__device__ inline unsigned short f2bf(float f) {
  union { bf16 h; unsigned short u; } cv;
  cv.h = __float2bfloat16(f);
  return cv.u;
}
__device__ inline float bf2f(bf16 h) { return __bfloat162float(h); }
__device__ inline float bfs(short u) {
  union { float f; unsigned u; } c;
  c.u = ((unsigned)(unsigned short)u) << 16;
  return c.f;
}

// ---------------------------------------------------------------- weights
__global__ void transpose_cvt(const float* __restrict__ src, bf16* __restrict__ dst,
                              int R, int C) {
  int i = blockIdx.x * 256 + threadIdx.x;
  if (i >= R * C) return;
  int c = i / R, r = i % R;
  dst[i] = __float2bfloat16(src[(size_t)r * C + c]);
}

__global__ void build_wq(const float* __restrict__ Woff, const float* __restrict__ Wattn,
                         const float* __restrict__ Wref, bf16* __restrict__ dst) {
  int i = blockIdx.x * 256 + threadIdx.x;   // 65536
  int n = i >> 8, k = i & 255;
  float v;
  if (n < 128)      v = Woff[k * 128 + n];
  else if (n < 192) v = Wattn[k * 64 + (n - 128)];
  else if (n < 194) v = Wref[k * 2 + (n - 192)];
  else              v = 0.f;
  dst[i] = __float2bfloat16(v);
}

// ---------------------------------------------------------------- elementwise cvt
__global__ void cvt_bf16_kernel(const float* __restrict__ src, bf16* __restrict__ dst, int n4) {
  int i = blockIdx.x * 256 + threadIdx.x;
  if (i >= n4) return;
  float4 v = ((const float4*)src)[i];
  ushort4 o;
  o.x = f2bf(v.x); o.y = f2bf(v.y); o.z = f2bf(v.z); o.w = f2bf(v.w);
  ((ushort4*)dst)[i] = o;
}

__global__ void addcvt_kernel(const float* __restrict__ a, const float* __restrict__ b,
                              bf16* __restrict__ dst, int n4) {
  int i = blockIdx.x * 256 + threadIdx.x;
  if (i >= n4) return;
  float4 va = ((const float4*)a)[i];
  float4 vb = ((const float4*)b)[i];
  ushort4 o;
  o.x = f2bf(va.x + vb.x); o.y = f2bf(va.y + vb.y);
  o.z = f2bf(va.z + vb.z); o.w = f2bf(va.w + vb.w);
  ((ushort4*)dst)[i] = o;
}

// ---------------------------------------------------------------- GEMM (persistent-B)
// C[M][N] = A[Mpad][K](bf16) x Bt[N][K](bf16)^T, K = KSEG*256.
// RATIONALE (r5-r12): seven variants with per-K-step LDS staging all pinned
// at MfmaUtil ~10% regardless of barriers/vmcnt/buffering/tile -> remove
// per-step staging entirely. Block = 256 thr / 4 waves, each wave owns 64
// M-rows (block 256 rows) x 64 N-cols. B-tile [64][256] = 32KB staged into
// LDS ONCE per K-segment (1-2 barriers per 256 K), A streamed global->reg
// with depth-1 chunk prefetch (transient 32 VGPR -- unlike r11's resident-B
// which regalloc refused to keep). Inner loop: ZERO barriers, ZERO staging.
// B LDS layout XOR-swizzled (chunk ^= row&7, involution; source pre-swizzled
// per m173 since global_load_lds writes linearly) -> 2-way bank conflicts
// (free) instead of 16-way at 512B rows.
// XCD chunk swizzle retained (consecutive wg share tm -> A-panel L2 reuse).
template<int KSEG, bool RELU>
__global__ void gemm_pb(const bf16* __restrict__ A, const bf16* __restrict__ Bt,
                        int K, int Ntiles, int N,
                        const float* __restrict__ bias, float biasScale,
                        const bf16* __restrict__ addB, float addScale,
                        bf16* __restrict__ outB, float* __restrict__ outF, int Mvalid) {
  __shared__ __align__(16) char smem[32768];   // B [64][256] bf16, swizzled
  const int tid  = threadIdx.x;
  const int wave = tid >> 6, lane = tid & 63;
  const int r = lane & 15, hi = lane >> 4;
  // XCD-aware chunked remap (bijective for any nwg)
  const int nwg = gridDim.x;
  const int orig = blockIdx.x;
  const int q8 = nwg >> 3, r8 = nwg & 7;
  const int xcd = orig & 7, idx = orig >> 3;
  const int wg = (xcd < r8 ? xcd * (q8 + 1) : r8 * (q8 + 1) + (xcd - r8) * q8) + idx;
  const int tm = wg / Ntiles, tn = wg % Ntiles;

  f32x4 acc[4][4];
#pragma unroll
  for (int i = 0; i < 4; ++i)
#pragma unroll
    for (int j = 0; j < 4; ++j) {
      f32x4 z = {0.f, 0.f, 0.f, 0.f};
      acc[i][j] = z;
    }

  const char* Bb = (const char*)Bt;
  const bf16* Abase = A + (size_t)(tm * 256 + wave * 64 + r) * K;   // + mf*16*K

#pragma unroll
  for (int seg = 0; seg < KSEG; ++seg) {
    if (seg) __syncthreads();              // all waves done reading previous B
    // stage B segment: 32KB, 8 wave-instrs/wave, source pre-swizzled
#pragma unroll
    for (int i = 0; i < 8; ++i) {
      const int p0 = (wave * 8 + i) << 10;
      const int pl = p0 + lane * 16;
      const int row = pl >> 9;             // 0..63 (B rows = C columns)
      const int chunk = (pl & 511) >> 4;   // 0..31
      const int srcoff = (chunk ^ (row & 7)) << 4;
      const char* g = Bb + ((size_t)(tn * 64 + row) * K + seg * 256) * 2 + srcoff;
      __builtin_amdgcn_global_load_lds(AS1(g), AS3(smem + p0), 16, 0, 0);
    }
    __syncthreads();                       // B resident (drains vmcnt)

    s16x8 af[4], afn[4];
#pragma unroll
    for (int mf = 0; mf < 4; ++mf)
      af[mf] = *(const s16x8*)(Abase + (size_t)(mf * 16) * K + seg * 256 + hi * 8);
#pragma unroll
    for (int kc = 0; kc < 8; ++kc) {
      if (kc < 7) {
#pragma unroll
        for (int mf = 0; mf < 4; ++mf)
          afn[mf] = *(const s16x8*)(Abase + (size_t)(mf * 16) * K + seg * 256 + (kc + 1) * 32 + hi * 8);
      }
#pragma unroll
      for (int nf = 0; nf < 4; ++nf) {
        const int row = nf * 16 + r;
        const s16x8 bfr = *(const s16x8*)(smem + row * 512 + (((kc * 4 + hi) ^ (r & 7)) << 4));
#pragma unroll
        for (int mf = 0; mf < 4; ++mf)
          acc[mf][nf] = __builtin_amdgcn_mfma_f32_16x16x32_bf16(af[mf], bfr, acc[mf][nf], 0, 0, 0);
      }
      if (kc < 7) {
#pragma unroll
        for (int mf = 0; mf < 4; ++mf) af[mf] = afn[mf];
      }
    }
  }

  // epilogue: C/D frag mapping col = lane&15, row = (lane>>4)*4 + j
#pragma unroll
  for (int mf = 0; mf < 4; ++mf) {
#pragma unroll
    for (int nf = 0; nf < 4; ++nf) {
      const int gn = tn * 64 + nf * 16 + r;
      const float bval = bias ? biasScale * bias[gn] : 0.f;
#pragma unroll
      for (int j2 = 0; j2 < 4; ++j2) {
        const int gm = tm * 256 + wave * 64 + mf * 16 + hi * 4 + j2;
        float v = acc[mf][nf][j2] + bval;
        if (addB && gm < Mvalid) v += addScale * bf2f(addB[(size_t)gm * N + gn]);
        if (RELU) v = fmaxf(v, 0.f);
        if (outB) outB[(size_t)gm * N + gn] = __float2bfloat16(v);
        if (outF && gm < Mvalid) outF[(size_t)gm * N + gn] = v;
      }
    }
  }
}

// ---------------------------------------------------------------- samp finalize
__global__ void finalize_kernel(const bf16* __restrict__ raw, const float* __restrict__ b_off,
                                const float* __restrict__ b_attn, const float* __restrict__ b_ref,
                                float* __restrict__ samp) {
  __shared__ float r[4][256];
  const int tid = threadIdx.x;
  const int q0 = blockIdx.x * 4;
#pragma unroll
  for (int i = 0; i < 4; ++i) {
    int e = tid + i * 256;
    int ql = e >> 8, k = e & 255;
    r[ql][k] = bf2f(raw[(size_t)(q0 + ql) * 256 + k]);
  }
  __syncthreads();
  const int ql = tid >> 6, hp = tid & 63;
  const int h = hp >> 3, p = hp & 7;
  float v[8];
  float m = -1e30f;
#pragma unroll
  for (int pp = 0; pp < 8; ++pp) {
    v[pp] = r[ql][128 + h * 8 + pp] + b_attn[h * 8 + pp];
    m = fmaxf(m, v[pp]);
  }
  float s = 0.f;
#pragma unroll
  for (int pp = 0; pp < 8; ++pp) { v[pp] = expf(v[pp] - m); s += v[pp]; }
  const float w = v[p] / s;
  const float sx = 1.f / (1.f + expf(-(r[ql][192] + b_ref[0])));
  const float sy = 1.f / (1.f + expf(-(r[ql][193] + b_ref[1])));
  const float px = sx * (float)BEV + (r[ql][hp * 2 + 0] + b_off[hp * 2 + 0]) - 0.5f;
  const float py = sy * (float)BEV + (r[ql][hp * 2 + 1] + b_off[hp * 2 + 1]) - 0.5f;
  const size_t o = ((size_t)(q0 + ql) * 64 + hp) * 3;
  samp[o] = px; samp[o + 1] = py; samp[o + 2] = w;
}

// ---------------------------------------------------------------- deform gather
__global__ __launch_bounds__(256, 4)
void deform_kernel(const float* __restrict__ samp, const bf16* __restrict__ val,
                   bf16* __restrict__ out) {
  __shared__ float s[8 * 192];
  const int tid = threadIdx.x;
  const int q0 = blockIdx.x * 8;
#pragma unroll
  for (int i = 0; i < 6; ++i) {
    const int e = tid + i * 256;
    s[e] = samp[(size_t)q0 * 192 + e];
  }
  __syncthreads();
  const int ql = tid >> 5;          // 0..7 query within block
  const int lane5 = tid & 31;
  const int h = lane5 >> 2;         // 0..7 head
  const int dg = lane5 & 3;         // 0..3 dword-group (8 channels)
  const float* sp = s + ql * 192 + h * 24;
  const bf16* vb = val + h * 32 + dg * 8;

  float acc[8] = {0.f, 0.f, 0.f, 0.f, 0.f, 0.f, 0.f, 0.f};
#pragma unroll 2
  for (int p = 0; p < 8; ++p) {
    const float px = sp[p * 3 + 0], py = sp[p * 3 + 1], w = sp[p * 3 + 2];
    const float xf = floorf(px), yf = floorf(py);
    const int x0 = (int)xf, y0 = (int)yf;
    const float lx = px - xf, ly = py - yf;
    const float xa = (x0 >= 0 && x0 < BEV) ? 1.f : 0.f;
    const float xb = (x0 + 1 >= 0 && x0 + 1 < BEV) ? 1.f : 0.f;
    const float ya = (y0 >= 0 && y0 < BEV) ? 1.f : 0.f;
    const float yb = (y0 + 1 >= 0 && y0 + 1 < BEV) ? 1.f : 0.f;
    const float w00 = w * (1.f - lx) * (1.f - ly) * xa * ya;
    const float w10 = w * lx * (1.f - ly) * xb * ya;
    const float w01 = w * (1.f - lx) * ly * xa * yb;
    const float w11 = w * lx * ly * xb * yb;
    const int cx0 = min(max(x0, 0), BEV - 1);
    const int cx1 = min(max(x0 + 1, 0), BEV - 1);
    const int cy0 = min(max(y0, 0), BEV - 1) * BEV;
    const int cy1 = min(max(y0 + 1, 0), BEV - 1) * BEV;
    const s16x8 v00 = *(const s16x8*)(vb + (size_t)(cy0 + cx0) * 256);
    const s16x8 v10 = *(const s16x8*)(vb + (size_t)(cy0 + cx1) * 256);
    const s16x8 v01 = *(const s16x8*)(vb + (size_t)(cy1 + cx0) * 256);
    const s16x8 v11 = *(const s16x8*)(vb + (size_t)(cy1 + cx1) * 256);
#pragma unroll
    for (int j = 0; j < 8; ++j) {
      acc[j] += w00 * bfs(v00[j]) + w10 * bfs(v10[j])
              + w01 * bfs(v01[j]) + w11 * bfs(v11[j]);
    }
  }
  s16x8 o;
#pragma unroll
  for (int j = 0; j < 8; ++j) o[j] = (short)f2bf(acc[j]);
  *(s16x8*)(out + (size_t)(q0 + ql) * 256 + h * 32 + dg * 8) = o;
}

// ---------------------------------------------------------------- host
extern "C" void kernel_launch(void* const* d_in, const int* in_sizes, int n_in,
                              void* d_out, int out_size, void* d_ws, size_t ws_size,
                              hipStream_t stream) {
  const float* B0     = (const float*)d_in[0];
  const float* B1     = (const float*)d_in[1];
  const float* qe     = (const float*)d_in[2];
  const float* W_ref  = (const float*)d_in[3];
  const float* b_ref  = (const float*)d_in[4];
  const float* W_off  = (const float*)d_in[5];
  const float* b_off  = (const float*)d_in[6];
  const float* W_attn = (const float*)d_in[7];
  const float* b_attn = (const float*)d_in[8];
  const float* W_val  = (const float*)d_in[9];
  const float* b_val  = (const float*)d_in[10];
  const float* W_out  = (const float*)d_in[11];
  const float* b_out  = (const float*)d_in[12];
  const float* W_ffn1 = (const float*)d_in[13];
  const float* b_ffn1 = (const float*)d_in[14];
  const float* W_ffn2 = (const float*)d_in[15];
  const float* b_ffn2 = (const float*)d_in[16];
  float* out = (float*)d_out;
  char* ws = (char*)d_ws;

  // workspace layout (bytes)
  const size_t SZ_MAT = (size_t)MPAD * 256 * 2;
  const size_t VAL_OFF    = 0;                          // val bf16
  const size_t RAW_OFF    = SZ_MAT;                     // raw / deform (aliased, serialized)
  const size_t BSH_OFF    = 2 * SZ_MAT;                 // Bshort bf16
  const size_t H_OFF      = 3 * SZ_MAT;                 // H [MPAD][1024] bf16 (82MB)
  const size_t QE_OFF     = H_OFF;                      // qe bf16 (aliased into H, used early)
  const size_t VSUM_OFF   = H_OFF + SZ_MAT;             // vsum bf16 (aliased into H)
  const size_t H_BYTES    = (size_t)MPAD * 1024 * 2;
  const size_t SAMP_OFF   = H_OFF + H_BYTES;            // samp f32 [NQ][64][3]
  const size_t SAMP_BYTES = (size_t)NQ * 192 * 4;
  const size_t WQ_OFF     = SAMP_OFF + SAMP_BYTES;
  const size_t WVAL_OFF   = WQ_OFF   + 256 * 256 * 2;
  const size_t WOUT_OFF   = WVAL_OFF + 256 * 256 * 2;
  const size_t WF1_OFF    = WOUT_OFF + 256 * 256 * 2;
  const size_t WF2_OFF    = WF1_OFF  + 1024 * 256 * 2;

  bf16* valb  = (bf16*)(ws + VAL_OFF);
  bf16* rawb  = (bf16*)(ws + RAW_OFF);
  bf16* defb  = rawb;                    // aliased (raw dead after finalize)
  bf16* bshb  = (bf16*)(ws + BSH_OFF);
  bf16* hbuf  = (bf16*)(ws + H_OFF);
  bf16* qeb   = (bf16*)(ws + QE_OFF);
  bf16* vsum  = (bf16*)(ws + VSUM_OFF);
  float* samp = (float*)(ws + SAMP_OFF);
  bf16* wq    = (bf16*)(ws + WQ_OFF);
  bf16* wval  = (bf16*)(ws + WVAL_OFF);
  bf16* wout  = (bf16*)(ws + WOUT_OFF);
  bf16* wf1   = (bf16*)(ws + WF1_OFF);
  bf16* wf2   = (bf16*)(ws + WF2_OFF);

  const int n4 = NQ * 256 / 4;           // 2,560,000
  const int MT = MPAD / 256;             // 157

  // weights -> transposed bf16
  build_wq<<<256, 256, 0, stream>>>(W_off, W_attn, W_ref, wq);
  transpose_cvt<<<(256 * 256 + 255) / 256, 256, 0, stream>>>(W_val, wval, 256, 256);
  transpose_cvt<<<(256 * 256 + 255) / 256, 256, 0, stream>>>(W_out, wout, 256, 256);
  transpose_cvt<<<(256 * 1024 + 255) / 256, 256, 0, stream>>>(W_ffn1, wf1, 256, 1024);
  transpose_cvt<<<(1024 * 256 + 255) / 256, 256, 0, stream>>>(W_ffn2, wf2, 1024, 256);

  // activations -> bf16
  cvt_bf16_kernel<<<n4 / 256, 256, 0, stream>>>(qe, qeb, n4);
  addcvt_kernel<<<n4 / 256, 256, 0, stream>>>(B0, B1, vsum, n4);

  // raw logits = q @ Wq^T
  gemm_pb<1, false><<<MT * 4, 256, 0, stream>>>(qeb, wq, 256, 4, 256,
                                                nullptr, 0.f, nullptr, 0.f,
                                                rawb, nullptr, NQ);
  finalize_kernel<<<NQ / 4, 256, 0, stream>>>(rawb, b_off, b_attn, b_ref, samp);

  // val = (B0+B1) @ W_val + 2*b_val
  gemm_pb<1, false><<<MT * 4, 256, 0, stream>>>(vsum, wval, 256, 4, 256,
                                                b_val, 2.f, nullptr, 0.f,
                                                valb, nullptr, NQ);

  deform_kernel<<<NQ / 8, 256, 0, stream>>>(samp, valb, defb);

  // B_short = deform @ W_out + 2*b_out + 2*q   (bf16 residual)
  gemm_pb<1, false><<<MT * 4, 256, 0, stream>>>(defb, wout, 256, 4, 256,
                                                b_out, 2.f, qeb, 2.f,
                                                bshb, nullptr, NQ);

  // H = relu(B_short @ W_ffn1 + b_ffn1)
  gemm_pb<1, true><<<MT * 16, 256, 0, stream>>>(bshb, wf1, 256, 16, 1024,
                                                b_ffn1, 1.f, nullptr, 0.f,
                                                hbuf, nullptr, NQ);

  // out = B_short + H @ W_ffn2 + b_ffn2   (K=1024 -> 4 segments)
  gemm_pb<4, false><<<MT * 4, 256, 0, stream>>>(hbuf, wf2, 1024, 4, 256,
                                                b_ffn2, 1.f, bshb, 1.f,
                                                nullptr, out, NQ);
}

// Round 15
// 300.995 us; speedup vs baseline: 1.7013x; 1.0512x over previous
//
#include <hip/hip_runtime.h>
#include <hip/hip_bf16.h>

#define NQ    40000
#define DD    256
#define NHH   8
#define NPP   8
#define DFF   1024
#define BEV   200
#define MPAD  40064   // 626 * 64 == 313 * 128

typedef __attribute__((ext_vector_type(4))) float f32x4;
typedef __attribute__((ext_vector_type(8))) short s16x8;
typedef __hip_bfloat16 bf16;

#define AS1(p) ((const __attribute__((address_space(1))) void*)(p))
#define AS3(p) ((__attribute__((address_space(3))) void*)(p))

__device__ inline unsigned short f2bf(float f) {
  union { bf16 h; unsigned short u; } cv;
  cv.h = __float2bfloat16(f);
  return cv.u;
}
__device__ inline float bf2f(bf16 h) { return __bfloat162float(h); }
__device__ inline float bfs(short u) {
  union { float f; unsigned u; } c;
  c.u = ((unsigned)(unsigned short)u) << 16;
  return c.f;
}

// ---------------------------------------------------------------- weights
__global__ void transpose_cvt(const float* __restrict__ src, bf16* __restrict__ dst,
                              int R, int C) {
  int i = blockIdx.x * 256 + threadIdx.x;
  if (i >= R * C) return;
  int c = i / R, r = i % R;
  dst[i] = __float2bfloat16(src[(size_t)r * C + c]);
}

__global__ void build_wq(const float* __restrict__ Woff, const float* __restrict__ Wattn,
                         const float* __restrict__ Wref, bf16* __restrict__ dst) {
  int i = blockIdx.x * 256 + threadIdx.x;   // 65536
  int n = i >> 8, k = i & 255;
  float v;
  if (n < 128)      v = Woff[k * 128 + n];
  else if (n < 192) v = Wattn[k * 64 + (n - 128)];
  else if (n < 194) v = Wref[k * 2 + (n - 192)];
  else              v = 0.f;
  dst[i] = __float2bfloat16(v);
}

// ---------------------------------------------------------------- elementwise cvt
__global__ void cvt_bf16_kernel(const float* __restrict__ src, bf16* __restrict__ dst, int n4) {
  int i = blockIdx.x * 256 + threadIdx.x;
  if (i >= n4) return;
  float4 v = ((const float4*)src)[i];
  ushort4 o;
  o.x = f2bf(v.x); o.y = f2bf(v.y); o.z = f2bf(v.z); o.w = f2bf(v.w);
  ((ushort4*)dst)[i] = o;
}

__global__ void addcvt_kernel(const float* __restrict__ a, const float* __restrict__ b,
                              bf16* __restrict__ dst, int n4) {
  int i = blockIdx.x * 256 + threadIdx.x;
  if (i >= n4) return;
  float4 va = ((const float4*)a)[i];
  float4 vb = ((const float4*)b)[i];
  ushort4 o;
  o.x = f2bf(va.x + vb.x); o.y = f2bf(va.y + vb.y);
  o.z = f2bf(va.z + vb.z); o.w = f2bf(va.w + vb.w);
  ((ushort4*)dst)[i] = o;
}

// ---------------------------------------------------------------- GEMM (persistent-A, K=256)
// C[M][N] = A[Mpad][256](bf16) x Bt[N][256](bf16)^T.
// RATIONALE (r5-r13): eight staged variants pinned at MfmaUtil ~10%; the ONE
// positive signal is K-amortization (r13 FFN2 at 4x MFMA per stage ran ~450
// TF vs ~300). So minimize staging/barrier frequency outright: block = 64
// M-rows, A[64][256]=32KB staged into LDS ONCE, ONE barrier, then the whole
// kernel is barrier-free: per kc, 4 swizzled ds_read (A) + 4 global B loads
// (depth-1 prefetch; weights L2-broadcast across all blocks) + 16 MFMA.
// Per wave: 1 barrier : 128 MFMA (16x better than r8, 4x than r13).
// A LDS chunk-XOR swizzle (chunk^=row&7; source pre-swizzled since
// global_load_lds writes linearly -- rule 21): ds_read 2-way conflict = free.
// WPB = waves/block: 4 (N=256, whole N in one block) or 8 (FFN1, Ntiles=2).
// (Resubmitted unchanged after round-14 container flake -- round-6 precedent.)
template<int WPB, bool RELU>
__global__ __launch_bounds__(WPB * 64)
void gemm_pa(const bf16* __restrict__ A, const bf16* __restrict__ Bt,
             int K, int Ntiles, int N,
             const float* __restrict__ bias, float biasScale,
             const bf16* __restrict__ addB, float addScale,
             bf16* __restrict__ outB, float* __restrict__ outF, int Mvalid) {
  __shared__ __align__(16) char smem[32768];   // A [64][256] bf16, swizzled
  const int tid  = threadIdx.x;
  const int wave = tid >> 6, lane = tid & 63;
  const int r = lane & 15, hi = lane >> 4;
  // XCD-aware chunked remap (bijective for any nwg)
  const int nwg = gridDim.x;
  const int orig = blockIdx.x;
  const int q8 = nwg >> 3, r8 = nwg & 7;
  const int xcd = orig & 7, idx = orig >> 3;
  const int wg = (xcd < r8 ? xcd * (q8 + 1) : r8 * (q8 + 1) + (xcd - r8) * q8) + idx;
  const int tm = wg / Ntiles, tn = wg % Ntiles;
  const int col0 = (tn * WPB + wave) * 64;     // this wave's 64 output cols

  // ---- stage A once (32KB): source pre-swizzled, LDS dest linear ----
  constexpr int SI = 32 / WPB;                 // 1KB wave-instrs per wave
#pragma unroll
  for (int i = 0; i < SI; ++i) {
    const int p0 = (wave * SI + i) << 10;
    const int pl = p0 + lane * 16;
    const int row = pl >> 9;                   // 0..63
    const int chunk = (pl & 511) >> 4;         // 0..31
    const char* g = (const char*)A + ((size_t)(tm * 64 + row) * K) * 2
                  + ((chunk ^ (row & 7)) << 4);
    __builtin_amdgcn_global_load_lds(AS1(g), AS3(smem + p0), 16, 0, 0);
  }
  __syncthreads();                             // the ONLY barrier

  f32x4 acc[4][4];
#pragma unroll
  for (int i = 0; i < 4; ++i)
#pragma unroll
    for (int j = 0; j < 4; ++j) {
      f32x4 z = {0.f, 0.f, 0.f, 0.f};
      acc[i][j] = z;
    }

  const char* Bb = (const char*)Bt;
  // ---- inner loop: zero barriers, zero staging ----
  s16x8 bf[4], bfn[4];
#pragma unroll
  for (int nf = 0; nf < 4; ++nf)
    bf[nf] = *(const s16x8*)(Bb + ((size_t)(col0 + nf * 16 + r) * K) * 2 + hi * 16);
#pragma unroll
  for (int kc = 0; kc < 8; ++kc) {
    if (kc < 7) {
#pragma unroll
      for (int nf = 0; nf < 4; ++nf)
        bfn[nf] = *(const s16x8*)(Bb + ((size_t)(col0 + nf * 16 + r) * K) * 2
                                  + (kc + 1) * 64 + hi * 16);
    }
    s16x8 af[4];
#pragma unroll
    for (int mf = 0; mf < 4; ++mf)
      af[mf] = *(const s16x8*)(smem + (mf * 16 + r) * 512
                               + (((kc * 4 + hi) ^ (r & 7)) << 4));
#pragma unroll
    for (int mf = 0; mf < 4; ++mf)
#pragma unroll
      for (int nf = 0; nf < 4; ++nf)
        acc[mf][nf] = __builtin_amdgcn_mfma_f32_16x16x32_bf16(af[mf], bf[nf], acc[mf][nf], 0, 0, 0);
    if (kc < 7) {
#pragma unroll
      for (int nf = 0; nf < 4; ++nf) bf[nf] = bfn[nf];
    }
  }

  // epilogue: C/D frag mapping col = lane&15, row = (lane>>4)*4 + j
#pragma unroll
  for (int mf = 0; mf < 4; ++mf) {
#pragma unroll
    for (int nf = 0; nf < 4; ++nf) {
      const int gn = col0 + nf * 16 + r;
      const float bval = bias ? biasScale * bias[gn] : 0.f;
#pragma unroll
      for (int j2 = 0; j2 < 4; ++j2) {
        const int gm = tm * 64 + mf * 16 + hi * 4 + j2;
        float v = acc[mf][nf][j2] + bval;
        if (addB && gm < Mvalid) v += addScale * bf2f(addB[(size_t)gm * N + gn]);
        if (RELU) v = fmaxf(v, 0.f);
        if (outB) outB[(size_t)gm * N + gn] = __float2bfloat16(v);
        if (outF && gm < Mvalid) outF[(size_t)gm * N + gn] = v;
      }
    }
  }
}

// ---------------------------------------------------------------- GEMM (r8 structure, for FFN2 K=1024)
// BK=32 double-buffer, issue-early, one __syncthreads per K-step.
template<int BK_, bool RELU>
__global__ void gemm_bt(const bf16* __restrict__ A, const bf16* __restrict__ Bt,
                        int K, int Ntiles, int N,
                        const float* __restrict__ bias, float biasScale,
                        const bf16* __restrict__ addB, float addScale,
                        bf16* __restrict__ outB, float* __restrict__ outF, int Mvalid) {
  constexpr int HALF = BK_ * 256;
  constexpr int ROWB = BK_ * 2;
  constexpr int BUFB = BK_ * 512;
  __shared__ __align__(16) char smem[2 * BUFB];
  const int tid  = threadIdx.x;
  const int wave = tid >> 6, lane = tid & 63;
  const int nwg = gridDim.x;
  const int orig = blockIdx.x;
  const int q8 = nwg >> 3, r8 = nwg & 7;
  const int xcd = orig & 7, idx = orig >> 3;
  const int wg = (xcd < r8 ? xcd * (q8 + 1) : r8 * (q8 + 1) + (xcd - r8) * q8) + idx;
  const int tm = wg / Ntiles, tn = wg % Ntiles;
  const int wr = wave >> 1, wc = wave & 1;

  f32x4 acc[4][4];
#pragma unroll
  for (int i = 0; i < 4; ++i)
#pragma unroll
    for (int j = 0; j < 4; ++j) {
      f32x4 z = {0.f, 0.f, 0.f, 0.f};
      acc[i][j] = z;
    }

  const char* Ab = (const char*)A;
  const char* Bb = (const char*)Bt;
  const int nK = K / BK_;

  auto stage = [&](int bufBase, int kt) {
    constexpr int WI = BK_ / 8;
#pragma unroll
    for (int i = 0; i < WI; ++i) {
      const int j  = wave * WI + i;
      const int p0 = j << 10;
      const char* g;
      if (p0 < HALF) {
        const int pl = p0 + lane * 16;
        const int row = pl / ROWB, cb = pl % ROWB;
        g = Ab + ((size_t)(tm * 128 + row) * K + kt * BK_) * 2 + cb;
      } else {
        const int pl = p0 - HALF + lane * 16;
        const int row = pl / ROWB, cb = pl % ROWB;
        g = Bb + ((size_t)(tn * 128 + row) * K + kt * BK_) * 2 + cb;
      }
      __builtin_amdgcn_global_load_lds(AS1(g), AS3(smem + bufBase + p0), 16, 0, 0);
    }
  };

  stage(0, 0);
  __syncthreads();
  int cur = 0;
  for (int kt = 0; kt < nK; ++kt) {
    if (kt + 1 < nK) stage((cur ^ 1) * BUFB, kt + 1);
    const char* sbuf = smem + cur * BUFB;
    constexpr int NKK = BK_ / 32;
#pragma unroll
    for (int kk = 0; kk < NKK; ++kk) {
      const int r  = lane & 15;
      const int kb = kk * 64 + (lane >> 4) * 16;
      s16x8 af[4], bfr[4];
#pragma unroll
      for (int mr = 0; mr < 4; ++mr)
        af[mr] = *(const s16x8*)(sbuf + (wr * 64 + mr * 16 + r) * ROWB + kb);
#pragma unroll
      for (int nr = 0; nr < 4; ++nr)
        bfr[nr] = *(const s16x8*)(sbuf + HALF + (wc * 64 + nr * 16 + r) * ROWB + kb);
#pragma unroll
      for (int mr = 0; mr < 4; ++mr)
#pragma unroll
        for (int nr = 0; nr < 4; ++nr)
          acc[mr][nr] = __builtin_amdgcn_mfma_f32_16x16x32_bf16(af[mr], bfr[nr], acc[mr][nr], 0, 0, 0);
    }
    __syncthreads();
    cur ^= 1;
  }

  const int r = lane & 15, rg = lane >> 4;
#pragma unroll
  for (int mr = 0; mr < 4; ++mr) {
#pragma unroll
    for (int nr = 0; nr < 4; ++nr) {
      const int gn = tn * 128 + wc * 64 + nr * 16 + r;
      const float bval = bias ? biasScale * bias[gn] : 0.f;
#pragma unroll
      for (int j2 = 0; j2 < 4; ++j2) {
        const int gm = tm * 128 + wr * 64 + mr * 16 + rg * 4 + j2;
        float v = acc[mr][nr][j2] + bval;
        if (addB && gm < Mvalid) v += addScale * bf2f(addB[(size_t)gm * N + gn]);
        if (RELU) v = fmaxf(v, 0.f);
        if (outB) outB[(size_t)gm * N + gn] = __float2bfloat16(v);
        if (outF && gm < Mvalid) outF[(size_t)gm * N + gn] = v;
      }
    }
  }
}

// ---------------------------------------------------------------- samp finalize
__global__ void finalize_kernel(const bf16* __restrict__ raw, const float* __restrict__ b_off,
                                const float* __restrict__ b_attn, const float* __restrict__ b_ref,
                                float* __restrict__ samp) {
  __shared__ float r[4][256];
  const int tid = threadIdx.x;
  const int q0 = blockIdx.x * 4;
#pragma unroll
  for (int i = 0; i < 4; ++i) {
    int e = tid + i * 256;
    int ql = e >> 8, k = e & 255;
    r[ql][k] = bf2f(raw[(size_t)(q0 + ql) * 256 + k]);
  }
  __syncthreads();
  const int ql = tid >> 6, hp = tid & 63;
  const int h = hp >> 3, p = hp & 7;
  float v[8];
  float m = -1e30f;
#pragma unroll
  for (int pp = 0; pp < 8; ++pp) {
    v[pp] = r[ql][128 + h * 8 + pp] + b_attn[h * 8 + pp];
    m = fmaxf(m, v[pp]);
  }
  float s = 0.f;
#pragma unroll
  for (int pp = 0; pp < 8; ++pp) { v[pp] = expf(v[pp] - m); s += v[pp]; }
  const float w = v[p] / s;
  const float sx = 1.f / (1.f + expf(-(r[ql][192] + b_ref[0])));
  const float sy = 1.f / (1.f + expf(-(r[ql][193] + b_ref[1])));
  const float px = sx * (float)BEV + (r[ql][hp * 2 + 0] + b_off[hp * 2 + 0]) - 0.5f;
  const float py = sy * (float)BEV + (r[ql][hp * 2 + 1] + b_off[hp * 2 + 1]) - 0.5f;
  const size_t o = ((size_t)(q0 + ql) * 64 + hp) * 3;
  samp[o] = px; samp[o + 1] = py; samp[o + 2] = w;
}

// ---------------------------------------------------------------- deform gather
__global__ __launch_bounds__(256, 4)
void deform_kernel(const float* __restrict__ samp, const bf16* __restrict__ val,
                   bf16* __restrict__ out) {
  __shared__ float s[8 * 192];
  const int tid = threadIdx.x;
  const int q0 = blockIdx.x * 8;
#pragma unroll
  for (int i = 0; i < 6; ++i) {
    const int e = tid + i * 256;
    s[e] = samp[(size_t)q0 * 192 + e];
  }
  __syncthreads();
  const int ql = tid >> 5;
  const int lane5 = tid & 31;
  const int h = lane5 >> 2;
  const int dg = lane5 & 3;
  const float* sp = s + ql * 192 + h * 24;
  const bf16* vb = val + h * 32 + dg * 8;

  float acc[8] = {0.f, 0.f, 0.f, 0.f, 0.f, 0.f, 0.f, 0.f};
#pragma unroll 2
  for (int p = 0; p < 8; ++p) {
    const float px = sp[p * 3 + 0], py = sp[p * 3 + 1], w = sp[p * 3 + 2];
    const float xf = floorf(px), yf = floorf(py);
    const int x0 = (int)xf, y0 = (int)yf;
    const float lx = px - xf, ly = py - yf;
    const float xa = (x0 >= 0 && x0 < BEV) ? 1.f : 0.f;
    const float xb = (x0 + 1 >= 0 && x0 + 1 < BEV) ? 1.f : 0.f;
    const float ya = (y0 >= 0 && y0 < BEV) ? 1.f : 0.f;
    const float yb = (y0 + 1 >= 0 && y0 + 1 < BEV) ? 1.f : 0.f;
    const float w00 = w * (1.f - lx) * (1.f - ly) * xa * ya;
    const float w10 = w * lx * (1.f - ly) * xb * ya;
    const float w01 = w * (1.f - lx) * ly * xa * yb;
    const float w11 = w * lx * ly * xb * yb;
    const int cx0 = min(max(x0, 0), BEV - 1);
    const int cx1 = min(max(x0 + 1, 0), BEV - 1);
    const int cy0 = min(max(y0, 0), BEV - 1) * BEV;
    const int cy1 = min(max(y0 + 1, 0), BEV - 1) * BEV;
    const s16x8 v00 = *(const s16x8*)(vb + (size_t)(cy0 + cx0) * 256);
    const s16x8 v10 = *(const s16x8*)(vb + (size_t)(cy0 + cx1) * 256);
    const s16x8 v01 = *(const s16x8*)(vb + (size_t)(cy1 + cx0) * 256);
    const s16x8 v11 = *(const s16x8*)(vb + (size_t)(cy1 + cx1) * 256);
#pragma unroll
    for (int j = 0; j < 8; ++j) {
      acc[j] += w00 * bfs(v00[j]) + w10 * bfs(v10[j])
              + w01 * bfs(v01[j]) + w11 * bfs(v11[j]);
    }
  }
  s16x8 o;
#pragma unroll
  for (int j = 0; j < 8; ++j) o[j] = (short)f2bf(acc[j]);
  *(s16x8*)(out + (size_t)(q0 + ql) * 256 + h * 32 + dg * 8) = o;
}

// ---------------------------------------------------------------- host
extern "C" void kernel_launch(void* const* d_in, const int* in_sizes, int n_in,
                              void* d_out, int out_size, void* d_ws, size_t ws_size,
                              hipStream_t stream) {
  const float* B0     = (const float*)d_in[0];
  const float* B1     = (const float*)d_in[1];
  const float* qe     = (const float*)d_in[2];
  const float* W_ref  = (const float*)d_in[3];
  const float* b_ref  = (const float*)d_in[4];
  const float* W_off  = (const float*)d_in[5];
  const float* b_off  = (const float*)d_in[6];
  const float* W_attn = (const float*)d_in[7];
  const float* b_attn = (const float*)d_in[8];
  const float* W_val  = (const float*)d_in[9];
  const float* b_val  = (const float*)d_in[10];
  const float* W_out  = (const float*)d_in[11];
  const float* b_out  = (const float*)d_in[12];
  const float* W_ffn1 = (const float*)d_in[13];
  const float* b_ffn1 = (const float*)d_in[14];
  const float* W_ffn2 = (const float*)d_in[15];
  const float* b_ffn2 = (const float*)d_in[16];
  float* out = (float*)d_out;
  char* ws = (char*)d_ws;

  // workspace layout (bytes)
  const size_t SZ_MAT = (size_t)MPAD * 256 * 2;        // 20,512,768
  const size_t VAL_OFF    = 0;
  const size_t RAW_OFF    = SZ_MAT;
  const size_t BSH_OFF    = 2 * SZ_MAT;
  const size_t H_OFF      = 3 * SZ_MAT;
  const size_t QE_OFF     = H_OFF;                      // qe bf16 (aliased into H, used early)
  const size_t VSUM_OFF   = H_OFF + SZ_MAT;             // vsum bf16 (aliased into H)
  const size_t H_BYTES    = (size_t)MPAD * 1024 * 2;
  const size_t SAMP_OFF   = H_OFF + H_BYTES;
  const size_t SAMP_BYTES = (size_t)NQ * 192 * 4;
  const size_t WQ_OFF     = SAMP_OFF + SAMP_BYTES;
  const size_t WVAL_OFF   = WQ_OFF   + 256 * 256 * 2;
  const size_t WOUT_OFF   = WVAL_OFF + 256 * 256 * 2;
  const size_t WF1_OFF    = WOUT_OFF + 256 * 256 * 2;
  const size_t WF2_OFF    = WF1_OFF  + 1024 * 256 * 2;

  bf16* valb  = (bf16*)(ws + VAL_OFF);
  bf16* rawb  = (bf16*)(ws + RAW_OFF);
  bf16* defb  = rawb;                    // aliased (raw dead after finalize)
  bf16* bshb  = (bf16*)(ws + BSH_OFF);
  bf16* hbuf  = (bf16*)(ws + H_OFF);
  bf16* qeb   = (bf16*)(ws + QE_OFF);
  bf16* vsum  = (bf16*)(ws + VSUM_OFF);
  float* samp = (float*)(ws + SAMP_OFF);
  bf16* wq    = (bf16*)(ws + WQ_OFF);
  bf16* wval  = (bf16*)(ws + WVAL_OFF);
  bf16* wout  = (bf16*)(ws + WOUT_OFF);
  bf16* wf1   = (bf16*)(ws + WF1_OFF);
  bf16* wf2   = (bf16*)(ws + WF2_OFF);

  const int n4 = NQ * 256 / 4;           // 2,560,000
  const int MT64 = MPAD / 64;            // 626
  const int MT128 = MPAD / 128;          // 313

  // weights -> transposed bf16
  build_wq<<<256, 256, 0, stream>>>(W_off, W_attn, W_ref, wq);
  transpose_cvt<<<(256 * 256 + 255) / 256, 256, 0, stream>>>(W_val, wval, 256, 256);
  transpose_cvt<<<(256 * 256 + 255) / 256, 256, 0, stream>>>(W_out, wout, 256, 256);
  transpose_cvt<<<(256 * 1024 + 255) / 256, 256, 0, stream>>>(W_ffn1, wf1, 256, 1024);
  transpose_cvt<<<(1024 * 256 + 255) / 256, 256, 0, stream>>>(W_ffn2, wf2, 1024, 256);

  // activations -> bf16
  cvt_bf16_kernel<<<n4 / 256, 256, 0, stream>>>(qe, qeb, n4);
  addcvt_kernel<<<n4 / 256, 256, 0, stream>>>(B0, B1, vsum, n4);

  // raw logits = q @ Wq^T   (persistent-A: 1 barrier/block)
  gemm_pa<4, false><<<MT64, 256, 0, stream>>>(qeb, wq, 256, 1, 256,
                                              nullptr, 0.f, nullptr, 0.f,
                                              rawb, nullptr, NQ);
  finalize_kernel<<<NQ / 4, 256, 0, stream>>>(rawb, b_off, b_attn, b_ref, samp);

  // val = (B0+B1) @ W_val + 2*b_val
  gemm_pa<4, false><<<MT64, 256, 0, stream>>>(vsum, wval, 256, 1, 256,
                                              b_val, 2.f, nullptr, 0.f,
                                              valb, nullptr, NQ);

  deform_kernel<<<NQ / 8, 256, 0, stream>>>(samp, valb, defb);

  // B_short = deform @ W_out + 2*b_out + 2*q   (bf16 residual)
  gemm_pa<4, false><<<MT64, 256, 0, stream>>>(defb, wout, 256, 1, 256,
                                              b_out, 2.f, qeb, 2.f,
                                              bshb, nullptr, NQ);

  // H = relu(B_short @ W_ffn1 + b_ffn1)   (persistent-A, 2 N-tiles of 512)
  gemm_pa<8, true><<<MT64 * 2, 512, 0, stream>>>(bshb, wf1, 256, 2, 1024,
                                                 b_ffn1, 1.f, nullptr, 0.f,
                                                 hbuf, nullptr, NQ);

  // out = B_short + H @ W_ffn2 + b_ffn2   (r8 structure control; sole f32 writer)
  gemm_bt<32, false><<<MT128 * 2, 256, 0, stream>>>(hbuf, wf2, 1024, 2, 256,
                                                    b_ffn2, 1.f, bshb, 1.f,
                                                    nullptr, out, NQ);
}

// Round 16
// 269.104 us; speedup vs baseline: 1.9029x; 1.1185x over previous
//
#include <hip/hip_runtime.h>
#include <hip/hip_bf16.h>

#define NQ    40000
#define DD    256
#define NHH   8
#define NPP   8
#define DFF   1024
#define BEV   200
#define MPAD  40064   // 626 * 64 == 313 * 128

typedef __attribute__((ext_vector_type(4))) float f32x4;
typedef __attribute__((ext_vector_type(8))) short s16x8;
typedef __hip_bfloat16 bf16;

#define AS1(p) ((const __attribute__((address_space(1))) void*)(p))
#define AS3(p) ((__attribute__((address_space(3))) void*)(p))

__device__ inline unsigned short f2bf(float f) {
  union { bf16 h; unsigned short u; } cv;
  cv.h = __float2bfloat16(f);
  return cv.u;
}
__device__ inline float bf2f(bf16 h) { return __bfloat162float(h); }
__device__ inline float bfs(short u) {
  union { float f; unsigned u; } c;
  c.u = ((unsigned)(unsigned short)u) << 16;
  return c.f;
}

// ---------------------------------------------------------------- weights
__global__ void transpose_cvt(const float* __restrict__ src, bf16* __restrict__ dst,
                              int R, int C) {
  int i = blockIdx.x * 256 + threadIdx.x;
  if (i >= R * C) return;
  int c = i / R, r = i % R;
  dst[i] = __float2bfloat16(src[(size_t)r * C + c]);
}

__global__ void build_wq(const float* __restrict__ Woff, const float* __restrict__ Wattn,
                         const float* __restrict__ Wref, bf16* __restrict__ dst) {
  int i = blockIdx.x * 256 + threadIdx.x;   // 65536
  int n = i >> 8, k = i & 255;
  float v;
  if (n < 128)      v = Woff[k * 128 + n];
  else if (n < 192) v = Wattn[k * 64 + (n - 128)];
  else if (n < 194) v = Wref[k * 2 + (n - 192)];
  else              v = 0.f;
  dst[i] = __float2bfloat16(v);
}

// ---------------------------------------------------------------- elementwise cvt (merged)
__global__ void cvt_both_kernel(const float* __restrict__ qe,
                                const float* __restrict__ a, const float* __restrict__ b,
                                bf16* __restrict__ qeb, bf16* __restrict__ vsum, int n4) {
  int i = blockIdx.x * 256 + threadIdx.x;
  if (i >= n4) return;
  float4 q4 = ((const float4*)qe)[i];
  ushort4 oq;
  oq.x = f2bf(q4.x); oq.y = f2bf(q4.y); oq.z = f2bf(q4.z); oq.w = f2bf(q4.w);
  ((ushort4*)qeb)[i] = oq;
  float4 va = ((const float4*)a)[i];
  float4 vb = ((const float4*)b)[i];
  ushort4 o;
  o.x = f2bf(va.x + vb.x); o.y = f2bf(va.y + vb.y);
  o.z = f2bf(va.z + vb.z); o.w = f2bf(va.w + vb.w);
  ((ushort4*)vsum)[i] = o;
}

// ---------------------------------------------------------------- GEMM (r8 structure)
// BK=32 double-buffer, issue-early, one __syncthreads per K-step. 128x128
// tile, 4 waves 2x2. Best-known structure (r8, 265us); nine scheduling
// variants (r9-r15) were null-to-negative -- the ~10% MfmaUtil is K=256
// shape-driven (fixed cost per block / nK), not schedule-driven.
template<int BK_, bool RELU>
__global__ void gemm_bt(const bf16* __restrict__ A, const bf16* __restrict__ Bt,
                        int K, int Ntiles, int N,
                        const float* __restrict__ bias, float biasScale,
                        const bf16* __restrict__ addB, float addScale,
                        bf16* __restrict__ outB, float* __restrict__ outF, int Mvalid) {
  constexpr int HALF = BK_ * 256;
  constexpr int ROWB = BK_ * 2;
  constexpr int BUFB = BK_ * 512;
  __shared__ __align__(16) char smem[2 * BUFB];
  const int tid  = threadIdx.x;
  const int wave = tid >> 6, lane = tid & 63;
  const int nwg = gridDim.x;
  const int orig = blockIdx.x;
  const int q8 = nwg >> 3, r8 = nwg & 7;
  const int xcd = orig & 7, idx = orig >> 3;
  const int wg = (xcd < r8 ? xcd * (q8 + 1) : r8 * (q8 + 1) + (xcd - r8) * q8) + idx;
  const int tm = wg / Ntiles, tn = wg % Ntiles;
  const int wr = wave >> 1, wc = wave & 1;

  f32x4 acc[4][4];
#pragma unroll
  for (int i = 0; i < 4; ++i)
#pragma unroll
    for (int j = 0; j < 4; ++j) {
      f32x4 z = {0.f, 0.f, 0.f, 0.f};
      acc[i][j] = z;
    }

  const char* Ab = (const char*)A;
  const char* Bb = (const char*)Bt;
  const int nK = K / BK_;

  auto stage = [&](int bufBase, int kt) {
    constexpr int WI = BK_ / 8;
#pragma unroll
    for (int i = 0; i < WI; ++i) {
      const int j  = wave * WI + i;
      const int p0 = j << 10;
      const char* g;
      if (p0 < HALF) {
        const int pl = p0 + lane * 16;
        const int row = pl / ROWB, cb = pl % ROWB;
        g = Ab + ((size_t)(tm * 128 + row) * K + kt * BK_) * 2 + cb;
      } else {
        const int pl = p0 - HALF + lane * 16;
        const int row = pl / ROWB, cb = pl % ROWB;
        g = Bb + ((size_t)(tn * 128 + row) * K + kt * BK_) * 2 + cb;
      }
      __builtin_amdgcn_global_load_lds(AS1(g), AS3(smem + bufBase + p0), 16, 0, 0);
    }
  };

  stage(0, 0);
  __syncthreads();
  int cur = 0;
  for (int kt = 0; kt < nK; ++kt) {
    if (kt + 1 < nK) stage((cur ^ 1) * BUFB, kt + 1);
    const char* sbuf = smem + cur * BUFB;
    constexpr int NKK = BK_ / 32;
#pragma unroll
    for (int kk = 0; kk < NKK; ++kk) {
      const int r  = lane & 15;
      const int kb = kk * 64 + (lane >> 4) * 16;
      s16x8 af[4], bfr[4];
#pragma unroll
      for (int mr = 0; mr < 4; ++mr)
        af[mr] = *(const s16x8*)(sbuf + (wr * 64 + mr * 16 + r) * ROWB + kb);
#pragma unroll
      for (int nr = 0; nr < 4; ++nr)
        bfr[nr] = *(const s16x8*)(sbuf + HALF + (wc * 64 + nr * 16 + r) * ROWB + kb);
#pragma unroll
      for (int mr = 0; mr < 4; ++mr)
#pragma unroll
        for (int nr = 0; nr < 4; ++nr)
          acc[mr][nr] = __builtin_amdgcn_mfma_f32_16x16x32_bf16(af[mr], bfr[nr], acc[mr][nr], 0, 0, 0);
    }
    __syncthreads();
    cur ^= 1;
  }

  const int r = lane & 15, rg = lane >> 4;
#pragma unroll
  for (int mr = 0; mr < 4; ++mr) {
#pragma unroll
    for (int nr = 0; nr < 4; ++nr) {
      const int gn = tn * 128 + wc * 64 + nr * 16 + r;
      const float bval = bias ? biasScale * bias[gn] : 0.f;
#pragma unroll
      for (int j2 = 0; j2 < 4; ++j2) {
        const int gm = tm * 128 + wr * 64 + mr * 16 + rg * 4 + j2;
        float v = acc[mr][nr][j2] + bval;
        if (addB && gm < Mvalid) v += addScale * bf2f(addB[(size_t)gm * N + gn]);
        if (RELU) v = fmaxf(v, 0.f);
        if (outB) outB[(size_t)gm * N + gn] = __float2bfloat16(v);
        if (outF && gm < Mvalid) outF[(size_t)gm * N + gn] = v;
      }
    }
  }
}

// ---------------------------------------------------------------- fused FFN1+FFN2
// out = Bsh + relu(Bsh@Wf1 + b1)@Wf2 + b2, H kept entirely in LDS.
// RATIONALE: r8's FFN1(K=256)=69us vs FFN2(K=1024)=45us, same structure &
// FLOPs -> the gap is per-block fixed cost / nK amortization, not schedule.
// Fusing doubles MFMA per block (1024/wave), eliminates H's 164MB HBM
// round-trip, and removes one kernel's fixed costs.
// Block = 64 M-rows x 256 out-cols, 4 waves (each 64x64 out, acc 4x4).
// 4 chunks of 256 H-cols: phase1 (r8-style dbuf, nK=8) computes
// H=relu(Bsh@Wf1c+b1) -> Hbuf LDS [64][272] (pad 16 el vs 256: 4-way banks);
// phase2 (r8-style dbuf, nK=8) out_acc += Hbuf @ Wf2c with af from Hbuf.
// LDS: staging 2x20KB + Hbuf 34.8KB = 74.8KB -> 2 blocks/CU (r8 regime).
__global__ __launch_bounds__(256)
void fused_ffn(const bf16* __restrict__ Bsh, const bf16* __restrict__ Wf1t,
               const bf16* __restrict__ Wf2t,
               const float* __restrict__ b1, const float* __restrict__ b2,
               float* __restrict__ outF, int Mvalid) {
  constexpr int BUFB = 20480;                  // A 4KB + B 16KB per buffer
  __shared__ __align__(16) char smem[2 * BUFB];
  __shared__ __align__(16) char hbuf[64 * 544];  // H [64][272] bf16 rows
  const int tid  = threadIdx.x;
  const int wave = tid >> 6, lane = tid & 63;
  const int r = lane & 15, hi = lane >> 4;
  // XCD-aware chunked remap
  const int nwg = gridDim.x;
  const int orig = blockIdx.x;
  const int q8 = nwg >> 3, r8_ = nwg & 7;
  const int xcd = orig & 7, idx = orig >> 3;
  const int tm = (xcd < r8_ ? xcd * (q8 + 1) : r8_ * (q8 + 1) + (xcd - r8_) * q8) + idx;

  f32x4 acc[4][4];                             // out accumulator (lives whole kernel)
#pragma unroll
  for (int i = 0; i < 4; ++i)
#pragma unroll
    for (int j = 0; j < 4; ++j) {
      f32x4 z = {0.f, 0.f, 0.f, 0.f};
      acc[i][j] = z;
    }

  const char* Ab = (const char*)Bsh;
  const char* W1 = (const char*)Wf1t;
  const char* W2 = (const char*)Wf2t;

  // stage1: A[64][32] (4KB) + Wf1t chunk [256 Hcols][32] (16KB); 20 instrs, 5/wave
  auto stage1 = [&](int bufBase, int chunk, int kt) {
#pragma unroll
    for (int i = 0; i < 5; ++i) {
      const int p0 = (wave * 5 + i) << 10;
      const char* g;
      if (p0 < 4096) {                         // A rows 64B
        const int pl = p0 + lane * 16;
        const int row = pl >> 6, cb = pl & 63;
        g = Ab + ((size_t)(tm * 64 + row) * 256 + kt * 32) * 2 + cb;
      } else {                                 // Wf1t rows (Hcols) 64B
        const int pl = p0 - 4096 + lane * 16;
        const int row = pl >> 6, cb = pl & 63;
        g = W1 + ((size_t)(chunk * 256 + row) * 256 + kt * 32) * 2 + cb;
      }
      __builtin_amdgcn_global_load_lds(AS1(g), AS3(smem + bufBase + p0), 16, 0, 0);
    }
  };
  // stage2: Wf2t chunk [256 outcols][32] (16KB); 16 instrs, 4/wave
  auto stage2 = [&](int bufBase, int chunk, int kt) {
#pragma unroll
    for (int i = 0; i < 4; ++i) {
      const int p0 = (wave * 4 + i) << 10;
      const int pl = p0 + lane * 16;
      const int row = pl >> 6, cb = pl & 63;
      const char* g = W2 + ((size_t)row * 1024 + chunk * 256 + kt * 32) * 2 + cb;
      __builtin_amdgcn_global_load_lds(AS1(g), AS3(smem + bufBase + p0), 16, 0, 0);
    }
  };

  for (int chunk = 0; chunk < 4; ++chunk) {
    // ---------- phase 1: acc_h = Bsh_rows @ Wf1t[chunk]^T ----------
    f32x4 acc_h[4][4];
#pragma unroll
    for (int i = 0; i < 4; ++i)
#pragma unroll
      for (int j = 0; j < 4; ++j) {
        f32x4 z = {0.f, 0.f, 0.f, 0.f};
        acc_h[i][j] = z;
      }
    stage1(0, chunk, 0);
    __syncthreads();
    int cur = 0;
    for (int kt = 0; kt < 8; ++kt) {
      if (kt + 1 < 8) stage1((cur ^ 1) * BUFB, chunk, kt + 1);
      const char* sbuf = smem + cur * BUFB;
      const int kb = hi * 16;
      s16x8 af[4], bfr[4];
#pragma unroll
      for (int mr = 0; mr < 4; ++mr)
        af[mr] = *(const s16x8*)(sbuf + (mr * 16 + r) * 64 + kb);
#pragma unroll
      for (int nr = 0; nr < 4; ++nr)
        bfr[nr] = *(const s16x8*)(sbuf + 4096 + (wave * 64 + nr * 16 + r) * 64 + kb);
#pragma unroll
      for (int mr = 0; mr < 4; ++mr)
#pragma unroll
        for (int nr = 0; nr < 4; ++nr)
          acc_h[mr][nr] = __builtin_amdgcn_mfma_f32_16x16x32_bf16(af[mr], bfr[nr], acc_h[mr][nr], 0, 0, 0);
      __syncthreads();
      cur ^= 1;
    }
    // write H = relu(acc_h + b1) to Hbuf [64][272] bf16
#pragma unroll
    for (int nr = 0; nr < 4; ++nr) {
      const int hcol = wave * 64 + nr * 16 + r;             // 0..255 local
      const float bv = b1[chunk * 256 + hcol];
#pragma unroll
      for (int mr = 0; mr < 4; ++mr)
#pragma unroll
        for (int j2 = 0; j2 < 4; ++j2) {
          const int row = mr * 16 + hi * 4 + j2;
          const float v = fmaxf(acc_h[mr][nr][j2] + bv, 0.f);
          *(unsigned short*)(hbuf + row * 544 + hcol * 2) = f2bf(v);
        }
    }
    __syncthreads();
    // ---------- phase 2: acc += Hbuf @ Wf2t[chunk]^T ----------
    stage2(0, chunk, 0);
    __syncthreads();
    cur = 0;
    for (int kt = 0; kt < 8; ++kt) {
      if (kt + 1 < 8) stage2((cur ^ 1) * BUFB, chunk, kt + 1);
      const char* sbuf = smem + cur * BUFB;
      const int kb = hi * 16;
      s16x8 af[4], bfr[4];
#pragma unroll
      for (int mr = 0; mr < 4; ++mr)
        af[mr] = *(const s16x8*)(hbuf + (mr * 16 + r) * 544 + kt * 64 + kb);
#pragma unroll
      for (int nr = 0; nr < 4; ++nr)
        bfr[nr] = *(const s16x8*)(sbuf + (wave * 64 + nr * 16 + r) * 64 + kb);
#pragma unroll
      for (int mr = 0; mr < 4; ++mr)
#pragma unroll
        for (int nr = 0; nr < 4; ++nr)
          acc[mr][nr] = __builtin_amdgcn_mfma_f32_16x16x32_bf16(af[mr], bfr[nr], acc[mr][nr], 0, 0, 0);
      __syncthreads();
      cur ^= 1;
    }
    __syncthreads();   // Hbuf consumed; safe to overwrite next chunk
  }

  // epilogue: out = acc + b2 + Bsh (residual), f32 to d_out
#pragma unroll
  for (int mr = 0; mr < 4; ++mr) {
#pragma unroll
    for (int nr = 0; nr < 4; ++nr) {
      const int gn = wave * 64 + nr * 16 + r;
      const float bval = b2[gn];
#pragma unroll
      for (int j2 = 0; j2 < 4; ++j2) {
        const int gm = tm * 64 + mr * 16 + hi * 4 + j2;
        if (gm < Mvalid) {
          float v = acc[mr][nr][j2] + bval + bf2f(Bsh[(size_t)gm * 256 + gn]);
          outF[(size_t)gm * 256 + gn] = v;
        }
      }
    }
  }
}

// ---------------------------------------------------------------- samp finalize
__global__ void finalize_kernel(const bf16* __restrict__ raw, const float* __restrict__ b_off,
                                const float* __restrict__ b_attn, const float* __restrict__ b_ref,
                                float* __restrict__ samp) {
  __shared__ float r[4][256];
  const int tid = threadIdx.x;
  const int q0 = blockIdx.x * 4;
#pragma unroll
  for (int i = 0; i < 4; ++i) {
    int e = tid + i * 256;
    int ql = e >> 8, k = e & 255;
    r[ql][k] = bf2f(raw[(size_t)(q0 + ql) * 256 + k]);
  }
  __syncthreads();
  const int ql = tid >> 6, hp = tid & 63;
  const int h = hp >> 3, p = hp & 7;
  float v[8];
  float m = -1e30f;
#pragma unroll
  for (int pp = 0; pp < 8; ++pp) {
    v[pp] = r[ql][128 + h * 8 + pp] + b_attn[h * 8 + pp];
    m = fmaxf(m, v[pp]);
  }
  float s = 0.f;
#pragma unroll
  for (int pp = 0; pp < 8; ++pp) { v[pp] = expf(v[pp] - m); s += v[pp]; }
  const float w = v[p] / s;
  const float sx = 1.f / (1.f + expf(-(r[ql][192] + b_ref[0])));
  const float sy = 1.f / (1.f + expf(-(r[ql][193] + b_ref[1])));
  const float px = sx * (float)BEV + (r[ql][hp * 2 + 0] + b_off[hp * 2 + 0]) - 0.5f;
  const float py = sy * (float)BEV + (r[ql][hp * 2 + 1] + b_off[hp * 2 + 1]) - 0.5f;
  const size_t o = ((size_t)(q0 + ql) * 64 + hp) * 3;
  samp[o] = px; samp[o + 1] = py; samp[o + 2] = w;
}

// ---------------------------------------------------------------- deform gather
__global__ __launch_bounds__(256, 4)
void deform_kernel(const float* __restrict__ samp, const bf16* __restrict__ val,
                   bf16* __restrict__ out) {
  __shared__ float s[8 * 192];
  const int tid = threadIdx.x;
  const int q0 = blockIdx.x * 8;
#pragma unroll
  for (int i = 0; i < 6; ++i) {
    const int e = tid + i * 256;
    s[e] = samp[(size_t)q0 * 192 + e];
  }
  __syncthreads();
  const int ql = tid >> 5;
  const int lane5 = tid & 31;
  const int h = lane5 >> 2;
  const int dg = lane5 & 3;
  const float* sp = s + ql * 192 + h * 24;
  const bf16* vb = val + h * 32 + dg * 8;

  float acc[8] = {0.f, 0.f, 0.f, 0.f, 0.f, 0.f, 0.f, 0.f};
#pragma unroll 2
  for (int p = 0; p < 8; ++p) {
    const float px = sp[p * 3 + 0], py = sp[p * 3 + 1], w = sp[p * 3 + 2];
    const float xf = floorf(px), yf = floorf(py);
    const int x0 = (int)xf, y0 = (int)yf;
    const float lx = px - xf, ly = py - yf;
    const float xa = (x0 >= 0 && x0 < BEV) ? 1.f : 0.f;
    const float xb = (x0 + 1 >= 0 && x0 + 1 < BEV) ? 1.f : 0.f;
    const float ya = (y0 >= 0 && y0 < BEV) ? 1.f : 0.f;
    const float yb = (y0 + 1 >= 0 && y0 + 1 < BEV) ? 1.f : 0.f;
    const float w00 = w * (1.f - lx) * (1.f - ly) * xa * ya;
    const float w10 = w * lx * (1.f - ly) * xb * ya;
    const float w01 = w * (1.f - lx) * ly * xa * yb;
    const float w11 = w * lx * ly * xb * yb;
    const int cx0 = min(max(x0, 0), BEV - 1);
    const int cx1 = min(max(x0 + 1, 0), BEV - 1);
    const int cy0 = min(max(y0, 0), BEV - 1) * BEV;
    const int cy1 = min(max(y0 + 1, 0), BEV - 1) * BEV;
    const s16x8 v00 = *(const s16x8*)(vb + (size_t)(cy0 + cx0) * 256);
    const s16x8 v10 = *(const s16x8*)(vb + (size_t)(cy0 + cx1) * 256);
    const s16x8 v01 = *(const s16x8*)(vb + (size_t)(cy1 + cx0) * 256);
    const s16x8 v11 = *(const s16x8*)(vb + (size_t)(cy1 + cx1) * 256);
#pragma unroll
    for (int j = 0; j < 8; ++j) {
      acc[j] += w00 * bfs(v00[j]) + w10 * bfs(v10[j])
              + w01 * bfs(v01[j]) + w11 * bfs(v11[j]);
    }
  }
  s16x8 o;
#pragma unroll
  for (int j = 0; j < 8; ++j) o[j] = (short)f2bf(acc[j]);
  *(s16x8*)(out + (size_t)(q0 + ql) * 256 + h * 32 + dg * 8) = o;
}

// ---------------------------------------------------------------- host
extern "C" void kernel_launch(void* const* d_in, const int* in_sizes, int n_in,
                              void* d_out, int out_size, void* d_ws, size_t ws_size,
                              hipStream_t stream) {
  const float* B0     = (const float*)d_in[0];
  const float* B1     = (const float*)d_in[1];
  const float* qe     = (const float*)d_in[2];
  const float* W_ref  = (const float*)d_in[3];
  const float* b_ref  = (const float*)d_in[4];
  const float* W_off  = (const float*)d_in[5];
  const float* b_off  = (const float*)d_in[6];
  const float* W_attn = (const float*)d_in[7];
  const float* b_attn = (const float*)d_in[8];
  const float* W_val  = (const float*)d_in[9];
  const float* b_val  = (const float*)d_in[10];
  const float* W_out  = (const float*)d_in[11];
  const float* b_out  = (const float*)d_in[12];
  const float* W_ffn1 = (const float*)d_in[13];
  const float* b_ffn1 = (const float*)d_in[14];
  const float* W_ffn2 = (const float*)d_in[15];
  const float* b_ffn2 = (const float*)d_in[16];
  float* out = (float*)d_out;
  char* ws = (char*)d_ws;

  // workspace layout (bytes)
  const size_t SZ_MAT = (size_t)MPAD * 256 * 2;        // 20,512,768
  const size_t VAL_OFF    = 0;
  const size_t RAW_OFF    = SZ_MAT;
  const size_t BSH_OFF    = 2 * SZ_MAT;
  const size_t QE_OFF     = 3 * SZ_MAT;
  const size_t VSUM_OFF   = 4 * SZ_MAT;
  const size_t SAMP_OFF   = 5 * SZ_MAT;                 // samp f32 [NQ][64][3]
  const size_t SAMP_BYTES = (size_t)NQ * 192 * 4;
  const size_t WQ_OFF     = SAMP_OFF + SAMP_BYTES;
  const size_t WVAL_OFF   = WQ_OFF   + 256 * 256 * 2;
  const size_t WOUT_OFF   = WVAL_OFF + 256 * 256 * 2;
  const size_t WF1_OFF    = WOUT_OFF + 256 * 256 * 2;
  const size_t WF2_OFF    = WF1_OFF  + 1024 * 256 * 2;

  bf16* valb  = (bf16*)(ws + VAL_OFF);
  bf16* rawb  = (bf16*)(ws + RAW_OFF);
  bf16* defb  = rawb;                    // aliased (raw dead after finalize)
  bf16* bshb  = (bf16*)(ws + BSH_OFF);
  bf16* qeb   = (bf16*)(ws + QE_OFF);
  bf16* vsum  = (bf16*)(ws + VSUM_OFF);
  float* samp = (float*)(ws + SAMP_OFF);
  bf16* wq    = (bf16*)(ws + WQ_OFF);
  bf16* wval  = (bf16*)(ws + WVAL_OFF);
  bf16* wout  = (bf16*)(ws + WOUT_OFF);
  bf16* wf1   = (bf16*)(ws + WF1_OFF);
  bf16* wf2   = (bf16*)(ws + WF2_OFF);

  const int n4 = NQ * 256 / 4;           // 2,560,000
  const int MT64 = MPAD / 64;            // 626
  const int MT128 = MPAD / 128;          // 313

  // weights -> transposed bf16
  build_wq<<<256, 256, 0, stream>>>(W_off, W_attn, W_ref, wq);
  transpose_cvt<<<(256 * 256 + 255) / 256, 256, 0, stream>>>(W_val, wval, 256, 256);
  transpose_cvt<<<(256 * 256 + 255) / 256, 256, 0, stream>>>(W_out, wout, 256, 256);
  transpose_cvt<<<(256 * 1024 + 255) / 256, 256, 0, stream>>>(W_ffn1, wf1, 256, 1024);
  transpose_cvt<<<(1024 * 256 + 255) / 256, 256, 0, stream>>>(W_ffn2, wf2, 1024, 256);

  // activations -> bf16 (merged)
  cvt_both_kernel<<<n4 / 256, 256, 0, stream>>>(qe, B0, B1, qeb, vsum, n4);

  // raw logits = q @ Wq^T
  gemm_bt<32, false><<<MT128 * 2, 256, 0, stream>>>(qeb, wq, 256, 2, 256,
                                                    nullptr, 0.f, nullptr, 0.f,
                                                    rawb, nullptr, NQ);
  finalize_kernel<<<NQ / 4, 256, 0, stream>>>(rawb, b_off, b_attn, b_ref, samp);

  // val = (B0+B1) @ W_val + 2*b_val
  gemm_bt<32, false><<<MT128 * 2, 256, 0, stream>>>(vsum, wval, 256, 2, 256,
                                                    b_val, 2.f, nullptr, 0.f,
                                                    valb, nullptr, NQ);

  deform_kernel<<<NQ / 8, 256, 0, stream>>>(samp, valb, defb);

  // B_short = deform @ W_out + 2*b_out + 2*q   (bf16 residual)
  gemm_bt<32, false><<<MT128 * 2, 256, 0, stream>>>(defb, wout, 256, 2, 256,
                                                    b_out, 2.f, qeb, 2.f,
                                                    bshb, nullptr, NQ);

  // out = B_short + relu(B_short@Wf1+b1)@Wf2 + b2   (fused, H in LDS)
  fused_ffn<<<MT64, 256, 0, stream>>>(bshb, wf1, wf2, b_ffn1, b_ffn2, out, NQ);
}